// Round 17
// baseline (223.087 us; speedup 1.0000x reference)
//
#include <hip/hip_runtime.h>

#define N_NODES 50000
#define N_EDGES 800000
#define NB_SCAN 196        // total 256-chunks = 7*25 + 21
#define NODES_PER_GRP 6400 // chunk-aligned (25 chunks of 256); groups 0..7, last has 5200
#define CHUNKS_PER_GRP 25
#define BUCKET_CAP 131072  // per-bucket capacity (mean ~102400)
#define CAST_BLOCKS 6250   // blocks doing cast/zero in cast_pack_k

typedef unsigned short ushort_t;
typedef unsigned char  uchar_t;
typedef __attribute__((ext_vector_type(8))) short  short8v;   // 8 bf16 (4 VGPR) MFMA A/B frag
typedef __attribute__((ext_vector_type(4))) float  float4v;   // MFMA C/D frag
typedef __attribute__((ext_vector_type(4))) unsigned short ushort4v;
typedef __attribute__((ext_vector_type(8))) unsigned short ushort8v;
typedef __attribute__((ext_vector_type(4))) int int4v;
typedef __attribute__((ext_vector_type(4))) unsigned char uchar4v;

__device__ __forceinline__ ushort_t f2bf(float f) {
    unsigned u = __float_as_uint(f);
    unsigned r = 0x7fffu + ((u >> 16) & 1u);   // round-to-nearest-even
    return (ushort_t)((u + r) >> 16);
}
__device__ __forceinline__ float bf2f(ushort_t h) {
    return __uint_as_float((unsigned)h << 16);
}

// ---- OCP fp8 e4m3fn encode (epilogue-side, RNE via 2^-120 scaling trick) ----
__device__ __forceinline__ uchar_t f2fp8(float f) {
    float a = fminf(fabsf(f), 448.f);
    unsigned u = __float_as_uint(a * 0x1p-120f);   // e4m3 em field lands at bits 20..26
    u += 0x7FFFFu + ((u >> 20) & 1u);              // RNE at bit 20
    unsigned em = (u >> 20) & 0x7Fu;
    unsigned sgn = (__float_as_uint(f) >> 24) & 0x80u;
    return (uchar_t)(sgn | em);
}
// ---- branch-free decode of byte k of a dword: raw value = true_value * 2^-120 ----
// (the 2^120 is folded into the final inv_deg scale; works for normals AND subnormals)
#define DEC0(w) __uint_as_float((((w) << 24) & 0x80000000u) | (((w) << 20) & 0x07f00000u))
#define DEC1(w) __uint_as_float((((w) << 16) & 0x80000000u) | (((w) << 12) & 0x07f00000u))
#define DEC2(w) __uint_as_float((((w) <<  8) & 0x80000000u) | (((w) <<  4) & 0x07f00000u))
#define DEC3(w) __uint_as_float((((w)      ) & 0x80000000u) | (((w) >>  4) & 0x07f00000u))

__device__ __forceinline__ void acc8_fp8(float* a, uint2 q) {
    a[0] += DEC0(q.x); a[1] += DEC1(q.x); a[2] += DEC2(q.x); a[3] += DEC3(q.x);
    a[4] += DEC0(q.y); a[5] += DEC1(q.y); a[6] += DEC2(q.y); a[7] += DEC3(q.y);
}

// ---------------- fused: cast x->bf16+fp8 + zero bcur  |  pack weights ----------------
__global__ __launch_bounds__(256) void cast_pack_k(const float* __restrict__ x,
                                                   ushort_t* __restrict__ xb,
                                                   uchar_t* __restrict__ xq,
                                                   int* __restrict__ bcur,
                                                   const float* __restrict__ W0n, const float* __restrict__ W0s,
                                                   const float* __restrict__ W1n, const float* __restrict__ W1s,
                                                   const float* __restrict__ W2n, const float* __restrict__ W2s,
                                                   ushort_t* __restrict__ P) {
    const int b = blockIdx.x, t = threadIdx.x;
    if (b < CAST_BLOCKS) {
        int i = b * 256 + t;
        if (i < N_NODES * 32) {
            float4 v = ((const float4*)x)[i];
            ushort4v h;
            h[0] = f2bf(v.x); h[1] = f2bf(v.y); h[2] = f2bf(v.z); h[3] = f2bf(v.w);
            ((ushort4v*)xb)[i] = h;
            uchar4v q;
            q[0] = f2fp8(v.x); q[1] = f2fp8(v.y); q[2] = f2fp8(v.z); q[3] = f2fp8(v.w);
            ((uchar4v*)xq)[i] = q;
        }
        if (i < 8) bcur[i] = 0;
        return;
    }
    // weight packing: fp32 W[128][DOUT] -> bf16 MFMA B-fragment layout
    int tid = (b - CAST_BLOCKS) * 256 + t;   // 0..10239
    const float* W; int dout; int base; int r;
    if      (tid < 2048)  { W = W0n; dout = 128; base = 0;     r = tid; }
    else if (tid < 4096)  { W = W0s; dout = 128; base = 16384; r = tid - 2048; }
    else if (tid < 6144)  { W = W1n; dout = 128; base = 32768; r = tid - 4096; }
    else if (tid < 8192)  { W = W1s; dout = 128; base = 49152; r = tid - 6144; }
    else if (tid < 9216)  { W = W2n; dout = 64;  base = 65536; r = tid - 8192; }
    else                  { W = W2s; dout = 64;  base = 73728; r = tid - 9216; }
    int lane = r & 63;
    int ks = (r >> 6) & 3;
    int nt = r >> 8;
    int col = nt * 16 + (lane & 15);
    int k0 = ks * 32 + ((lane >> 4) << 3);
    ushort_t* d = P + (size_t)base + (size_t)r * 8;
    ushort4v lo4, hi4;
#pragma unroll
    for (int j = 0; j < 4; ++j) lo4[j] = f2bf(W[(size_t)(k0 + j) * dout + col]);
#pragma unroll
    for (int j = 0; j < 4; ++j) hi4[j] = f2bf(W[(size_t)(k0 + 4 + j) * dout + col]);
    *(ushort4v*)d = lo4;
    *(ushort4v*)(d + 4) = hi4;
}

// ---------------- edge bucketing: 782 blocks x 4 edges/thread ----------------
__global__ __launch_bounds__(256) void bucket_k(const int4v* __restrict__ dst4,
                                                const int4v* __restrict__ src4,
                                                int* __restrict__ bcur,
                                                int2* __restrict__ buckets) {
    __shared__ int lcount[8];
    __shared__ int lbase[8];
    const int t = threadIdx.x, b = blockIdx.x;
    if (t < 8) lcount[t] = 0;
    __syncthreads();

    const int idx = b * 256 + t;   // int4 index, n4 = 200000
    int4v d, s;
    if (idx < N_EDGES / 4) {
        d = __builtin_nontemporal_load(dst4 + idx);
        s = __builtin_nontemporal_load(src4 + idx);
    } else {
        d[0] = d[1] = d[2] = d[3] = -1;
        s[0] = s[1] = s[2] = s[3] = 0;
    }
    int g[4], li[4];
#pragma unroll
    for (int j = 0; j < 4; ++j) {
        int dv = d[j];
        g[j] = (dv >= 0) ? (dv / NODES_PER_GRP) : -1;
        li[j] = (g[j] >= 0) ? atomicAdd(&lcount[g[j]], 1) : 0;
    }
    __syncthreads();
    if (t < 8) lbase[t] = atomicAdd(bcur + t, lcount[t]);
    __syncthreads();
#pragma unroll
    for (int j = 0; j < 4; ++j) {
        if (g[j] >= 0) {
            int pos = lbase[g[j]] + li[j];
            buckets[(size_t)g[j] * BUCKET_CAP + pos] = make_int2(d[j], s[j]);
        }
    }
}

// ---------------- atomic-free degree + chunk sums ----------------
__global__ __launch_bounds__(1024) void deg_hist_k(const int* __restrict__ bcur,
                                                   const int2* __restrict__ buckets,
                                                   int* __restrict__ deg,
                                                   int* __restrict__ bsum) {
    __shared__ int hist[NODES_PER_GRP];
    const int g = blockIdx.x;
    const int t = threadIdx.x;
    const int lo = g * NODES_PER_GRP;
    const int cnt = bcur[g];
    const int2* bk = buckets + (size_t)g * BUCKET_CAP;
    for (int i = t; i < NODES_PER_GRP; i += 1024) hist[i] = 0;
    __syncthreads();
    for (int i = t; i < cnt; i += 1024) {
        atomicAdd(&hist[bk[i].x - lo], 1);
    }
    __syncthreads();
    const int nNodes = (N_NODES - lo < NODES_PER_GRP) ? (N_NODES - lo) : NODES_PER_GRP;
    for (int i = t; i < nNodes; i += 1024) deg[lo + i] = hist[i];
    const int wave = t >> 6, lane = t & 63;
    const int nch = (nNodes + 255) >> 8;
    for (int c = wave; c < nch; c += 16) {
        int base = c * 256 + lane;
        int s = hist[base] + hist[base + 64] + hist[base + 128] + hist[base + 192];
#pragma unroll
        for (int off = 32; off > 0; off >>= 1) s += __shfl_xor(s, off);
        if (lane == 0) bsum[g * CHUNKS_PER_GRP + c] = s;
    }
}

// ---------------- fused rowptr ----------------
__global__ __launch_bounds__(256) void rowptr_fused_k(const int* __restrict__ deg,
                                                      const int* __restrict__ bsum,
                                                      int* __restrict__ rowptr,
                                                      int* __restrict__ cursor,
                                                      float* __restrict__ inv) {
    __shared__ int sb[256];
    __shared__ int s[256];
    const int t = threadIdx.x, b = blockIdx.x;
    int v = (t < NB_SCAN) ? bsum[t] : 0;
    sb[t] = v;
    __syncthreads();
#pragma unroll
    for (int off = 1; off < 256; off <<= 1) {
        int u = (t >= off) ? sb[t - off] : 0;
        __syncthreads();
        sb[t] += u;
        __syncthreads();
    }
    const int boffb = (b == 0) ? 0 : sb[b - 1];
    if (b == NB_SCAN - 1 && t == 0) rowptr[N_NODES] = sb[NB_SCAN - 1];

    int i = b * 256 + t;
    int d = (i < N_NODES) ? deg[i] : 0;
    s[t] = d;
    __syncthreads();
#pragma unroll
    for (int off = 1; off < 256; off <<= 1) {
        int u = (t >= off) ? s[t - off] : 0;
        __syncthreads();
        s[t] += u;
        __syncthreads();
    }
    if (i < N_NODES) {
        int r = boffb + s[t] - d;
        rowptr[i] = r;
        cursor[i] = r;
        inv[i] = 1.0f / fmaxf((float)d, 1.0f);
    }
}

// ---------------- scatter from buckets ----------------
__global__ __launch_bounds__(256) void scatter_bucket_k(const int* __restrict__ bcur,
                                                        const int2* __restrict__ buckets,
                                                        int* __restrict__ cursor,
                                                        int* __restrict__ csr) {
    const int grp = blockIdx.x & 7;
    const int cnt = bcur[grp];
    const int2* bk = buckets + (size_t)grp * BUCKET_CAP;
    const int stride = (gridDim.x >> 3) * 256;
    for (int i = (blockIdx.x >> 3) * 256 + threadIdx.x; i < cnt; i += stride) {
        int2 e = bk[i];
        csr[atomicAdd(cursor + e.x, 1)] = e.y;
    }
}

// ---------------- FUSED fp8-gather-mean + dual-A GEMM ----------------
// Gather reads the fp8 shadow copy Hq (128 B/row, half the bytes of bf16); decode is
// branch-free with the 2^120 scale folded into inv_deg. WQ: also write fp8 copy of output.
template <bool WQ>
__global__ __launch_bounds__(256, 4) void gathergemm_k(const ushort_t* __restrict__ H,
                                                       const uchar_t* __restrict__ Hq,
                                                       const int* __restrict__ rowptr,
                                                       const int* __restrict__ csr,
                                                       const float* __restrict__ inv,
                                                       const short8v* __restrict__ Ws,
                                                       const short8v* __restrict__ Wn,
                                                       const float* __restrict__ bias,
                                                       ushort_t* __restrict__ Out,
                                                       uchar_t* __restrict__ OutQ, int N) {
    __shared__ ushort_t sm[2][64 * 128];   // 2 x 16 KB
    char* sbH = (char*)sm[0];
    char* sbM = (char*)sm[1];
    const int bm = blockIdx.x * 64;
    const int t = threadIdx.x;
    const int w = t >> 6, l = t & 63;
    const ushort8v* Hp = (const ushort8v*)H;   // row stride 16 (256 B)
    const uint2* Qp = (const uint2*)Hq;        // row stride 16 (128 B)
    ushort8v zeroV = {0, 0, 0, 0, 0, 0, 0, 0};

    // stage H tile (swizzled)
#pragma unroll
    for (int it = 0; it < 4; ++it) {
        int r = it * 16 + (t >> 4);
        int row = bm + r;
        int byte = (r * 256 + (t & 15) * 16) ^ ((r & 7) << 4);
        ushort8v vh = zeroV;
        if (row < N) vh = Hp[(size_t)row * 16 + (t & 15)];
        *(ushort8v*)(sbH + byte) = vh;
    }

    // fp8 gather-mean M tile straight into swizzled LDS: 16 lanes per row, lane c owns cols [8c,8c+8)
    const int c = t & 15;
#pragma unroll
    for (int pass = 0; pass < 4; ++pass) {
        int r = pass * 16 + (t >> 4);
        int row = bm + r;
        int byte = (r * 256 + c * 16) ^ ((r & 7) << 4);
        ushort8v o = zeroV;
        if (row < N) {
            int start = rowptr[row], end = rowptr[row + 1];
            float a0[8] = {}, a1[8] = {}, a2[8] = {}, a3[8] = {};
            int j = start;
            for (; j + 3 < end; j += 4) {
                int u0 = csr[j], u1 = csr[j + 1], u2 = csr[j + 2], u3 = csr[j + 3];
                uint2 q0 = Qp[(size_t)u0 * 16 + c];
                uint2 q1 = Qp[(size_t)u1 * 16 + c];
                uint2 q2 = Qp[(size_t)u2 * 16 + c];
                uint2 q3 = Qp[(size_t)u3 * 16 + c];
                acc8_fp8(a0, q0); acc8_fp8(a1, q1);
                acc8_fp8(a2, q2); acc8_fp8(a3, q3);
            }
            for (; j < end; ++j) {
                uint2 q = Qp[(size_t)csr[j] * 16 + c];
                acc8_fp8(a0, q);
            }
            float scf = inv[row] * 0x1p120f;   // undo the 2^-120 decode scale
#pragma unroll
            for (int k = 0; k < 8; ++k) o[k] = f2bf(((a0[k] + a1[k]) + (a2[k] + a3[k])) * scf);
        }
        *(ushort8v*)(sbM + byte) = o;
    }
    __syncthreads();

    float bv[8];
#pragma unroll
    for (int nt = 0; nt < 8; ++nt) bv[nt] = bias[nt * 16 + (l & 15)];

    float4v acc[8] = {};
#pragma unroll
    for (int ks = 0; ks < 4; ++ks) {
        int r0 = w * 16 + (l & 15);
        int b0 = (r0 * 256 + ks * 64 + (l >> 4) * 16) ^ ((r0 & 7) << 4);
        short8v ah = *(const short8v*)(sbH + b0);
        short8v am = *(const short8v*)(sbM + b0);
#pragma unroll
        for (int nt = 0; nt < 8; ++nt) {
            short8v bs = Ws[(nt * 4 + ks) * 64 + l];
            short8v bn = Wn[(nt * 4 + ks) * 64 + l];
            acc[nt] = __builtin_amdgcn_mfma_f32_16x16x32_bf16(ah, bs, acc[nt], 0, 0, 0);
            acc[nt] = __builtin_amdgcn_mfma_f32_16x16x32_bf16(am, bn, acc[nt], 0, 0, 0);
        }
    }

    // C/D layout: col = lane&15, row = (lane>>4)*4 + i  [verified m89]
#pragma unroll
    for (int i = 0; i < 4; ++i) {
        int row = bm + w * 16 + (l >> 4) * 4 + i;
        if (row < N) {
#pragma unroll
            for (int nt = 0; nt < 8; ++nt) {
                int col = nt * 16 + (l & 15);
                float v = fmaxf(acc[nt][i] + bv[nt], 0.f);
                Out[(size_t)row * 128 + col] = f2bf(v);
                if (WQ) OutQ[(size_t)row * 128 + col] = f2fp8(v);
            }
        }
    }
}

// ---------------- layer-2 dual GEMM: S(fp32,->out) = H@Wself + b ; Z(bf16) = H@Wneigh ----------------
__global__ __launch_bounds__(256, 4) void dual64_k(const ushort_t* __restrict__ A,
                                                   const short8v* __restrict__ Wn,
                                                   const short8v* __restrict__ Ws,
                                                   const float* __restrict__ bias,
                                                   ushort_t* __restrict__ Z,
                                                   float* __restrict__ S, int N) {
    constexpr int NT = 4;
    __shared__ ushort_t Asm[64 * 128];   // 16 KB
    char* sb = (char*)Asm;
    const int bm = blockIdx.x * 64;
    const int t = threadIdx.x;
    const int w = t >> 6, l = t & 63;

    {
        const ushort8v* Ap = (const ushort8v*)A;
        ushort8v zeroV = {0, 0, 0, 0, 0, 0, 0, 0};
#pragma unroll
        for (int it = 0; it < 4; ++it) {
            int r = it * 16 + (t >> 4);
            int row = bm + r;
            ushort8v v = zeroV;
            if (row < N) v = Ap[(size_t)row * 16 + (t & 15)];
            int byte = (r * 256 + (t & 15) * 16) ^ ((r & 7) << 4);
            *(ushort8v*)(sb + byte) = v;
        }
    }
    __syncthreads();

    float bv[NT];
#pragma unroll
    for (int nt = 0; nt < NT; ++nt) bv[nt] = bias[nt * 16 + (l & 15)];

    float4v accS[NT] = {}, accN[NT] = {};
#pragma unroll
    for (int ks = 0; ks < 4; ++ks) {
        int r0 = w * 16 + (l & 15);
        int b0 = (r0 * 256 + ks * 64 + (l >> 4) * 16) ^ ((r0 & 7) << 4);
        short8v a = *(const short8v*)(sb + b0);
#pragma unroll
        for (int nt = 0; nt < NT; ++nt) {
            short8v bs = Ws[(nt * 4 + ks) * 64 + l];
            short8v bn = Wn[(nt * 4 + ks) * 64 + l];
            accS[nt] = __builtin_amdgcn_mfma_f32_16x16x32_bf16(a, bs, accS[nt], 0, 0, 0);
            accN[nt] = __builtin_amdgcn_mfma_f32_16x16x32_bf16(a, bn, accN[nt], 0, 0, 0);
        }
    }

#pragma unroll
    for (int i = 0; i < 4; ++i) {
        int row = bm + w * 16 + (l >> 4) * 4 + i;
        if (row < N) {
#pragma unroll
            for (int nt = 0; nt < NT; ++nt) {
                int col = nt * 16 + (l & 15);
                S[(size_t)row * 64 + col] = accS[nt][i] + bv[nt];
                Z[(size_t)row * 64 + col] = f2bf(accN[nt][i]);
            }
        }
    }
}

// ---------------- layer-2 aggregation: out(fp32,=S) += inv * sum z[nbr]  (64-wide, bf16) ----------------
__global__ __launch_bounds__(256) void agg64_k(const ushort_t* __restrict__ z,
                                               const int* __restrict__ rowptr,
                                               const int* __restrict__ csr,
                                               const float* __restrict__ inv,
                                               float* __restrict__ out, int N) {
    int node = (blockIdx.x * 256 + threadIdx.x) >> 3;
    int c = threadIdx.x & 7;
    if (node >= N) return;
    int start = rowptr[node], end = rowptr[node + 1];

    const ushort8v* zp = (const ushort8v*)z;   // row stride 8 (128 B)
    float a0[8] = {}, a1[8] = {}, a2[8] = {}, a3[8] = {};
    int j = start;
    for (; j + 3 < end; j += 4) {
        int u0 = csr[j], u1 = csr[j + 1], u2 = csr[j + 2], u3 = csr[j + 3];
        ushort8v w0 = zp[(size_t)u0 * 8 + c];
        ushort8v w1 = zp[(size_t)u1 * 8 + c];
        ushort8v w2 = zp[(size_t)u2 * 8 + c];
        ushort8v w3 = zp[(size_t)u3 * 8 + c];
#pragma unroll
        for (int k = 0; k < 8; ++k) {
            a0[k] += bf2f(w0[k]); a1[k] += bf2f(w1[k]);
            a2[k] += bf2f(w2[k]); a3[k] += bf2f(w3[k]);
        }
    }
    for (; j < end; ++j) {
        ushort8v w = zp[(size_t)csr[j] * 8 + c];
#pragma unroll
        for (int k = 0; k < 8; ++k) a0[k] += bf2f(w[k]);
    }
    float s = inv[node];
    float* op = out + (size_t)node * 64 + c * 8;
    float4 o0 = *(float4*)op;
    float4 o1 = *(float4*)(op + 4);
    o0.x += ((a0[0] + a1[0]) + (a2[0] + a3[0])) * s;
    o0.y += ((a0[1] + a1[1]) + (a2[1] + a3[1])) * s;
    o0.z += ((a0[2] + a1[2]) + (a2[2] + a3[2])) * s;
    o0.w += ((a0[3] + a1[3]) + (a2[3] + a3[3])) * s;
    o1.x += ((a0[4] + a1[4]) + (a2[4] + a3[4])) * s;
    o1.y += ((a0[5] + a1[5]) + (a2[5] + a3[5])) * s;
    o1.z += ((a0[6] + a1[6]) + (a2[6] + a3[6])) * s;
    o1.w += ((a0[7] + a1[7]) + (a2[7] + a3[7])) * s;
    *(float4*)op = o0;
    *(float4*)(op + 4) = o1;
}

// ---------------- launch ----------------

extern "C" void kernel_launch(void* const* d_in, const int* in_sizes, int n_in,
                              void* d_out, int out_size, void* d_ws, size_t ws_size,
                              hipStream_t stream) {
    const float* x       = (const float*)d_in[0];
    const int*   src     = (const int*)d_in[1];
    const int*   dst     = (const int*)d_in[2];
    const float* Wself0  = (const float*)d_in[3];
    const float* Wneigh0 = (const float*)d_in[4];
    const float* b0      = (const float*)d_in[5];
    const float* Wself1  = (const float*)d_in[6];
    const float* Wneigh1 = (const float*)d_in[7];
    const float* b1      = (const float*)d_in[8];
    const float* Wself2  = (const float*)d_in[9];
    const float* Wneigh2 = (const float*)d_in[10];
    const float* b2      = (const float*)d_in[11];
    float* out = (float*)d_out;

    char* ws = (char*)d_ws;
    size_t off = 0;
    auto alloc = [&](size_t bytes) -> void* {
        void* p = ws + off;
        off += (bytes + 255) & ~(size_t)255;
        return p;
    };
    int*      deg     = (int*)alloc((size_t)N_NODES * 4);
    float*    inv     = (float*)alloc((size_t)N_NODES * 4);
    int*      rowptr  = (int*)alloc((size_t)(N_NODES + 1) * 4);
    int*      cursor  = (int*)alloc((size_t)N_NODES * 4);
    int*      csr     = (int*)alloc((size_t)N_EDGES * 4);
    int*      bsum    = (int*)alloc((size_t)NB_SCAN * 4);
    int*      bcur    = (int*)alloc((size_t)8 * 4);
    int2*     buckets = (int2*)alloc((size_t)8 * BUCKET_CAP * 8);
    ushort_t* packW   = (ushort_t*)alloc((size_t)81920 * 2);
    ushort_t* xb      = (ushort_t*)alloc((size_t)N_NODES * 128 * 2);
    uchar_t*  xq      = (uchar_t*)alloc((size_t)N_NODES * 128);
    ushort_t* h1      = (ushort_t*)alloc((size_t)N_NODES * 128 * 2);
    uchar_t*  h1q     = (uchar_t*)alloc((size_t)N_NODES * 128);
    ushort_t* h2      = (ushort_t*)alloc((size_t)N_NODES * 128 * 2);
    ushort_t* z64     = (ushort_t*)alloc((size_t)N_NODES * 64 * 2);

    dim3 b256(256);
    const int gemmBlocks   = (N_NODES + 63) / 64;          // 782 (64-row tiles, 4 blocks/CU)
    const int agg64Blocks  = (N_NODES * 8 + 255) / 256;    // 1563
    const int bucketBlocks = (N_EDGES / 4 + 255) / 256;    // 782 (4 edges/thread)

    // ---- CSR build: cast+pack | bucket | LDS-hist deg+chunk-sums | rowptr | scatter ----
    cast_pack_k<<<CAST_BLOCKS + 40, b256, 0, stream>>>(x, xb, xq, bcur,
                                                       Wneigh0, Wself0, Wneigh1, Wself1,
                                                       Wneigh2, Wself2, packW);
    bucket_k<<<bucketBlocks, b256, 0, stream>>>((const int4v*)dst, (const int4v*)src,
                                                bcur, buckets);
    deg_hist_k<<<8, dim3(1024), 0, stream>>>(bcur, buckets, deg, bsum);
    rowptr_fused_k<<<NB_SCAN, b256, 0, stream>>>(deg, bsum, rowptr, cursor, inv);
    scatter_bucket_k<<<512, b256, 0, stream>>>(bcur, buckets, cursor, csr);

    const short8v* pN0 = (const short8v*)(packW);
    const short8v* pS0 = (const short8v*)(packW + 16384);
    const short8v* pN1 = (const short8v*)(packW + 32768);
    const short8v* pS1 = (const short8v*)(packW + 49152);
    const short8v* pN2 = (const short8v*)(packW + 65536);
    const short8v* pS2 = (const short8v*)(packW + 73728);

    // layer 0: h1 = relu(xb@Ws0 + mean_fp8(xq[nbr])@Wn0 + b0); also writes h1q (fp8 shadow)
    gathergemm_k<true><<<gemmBlocks, b256, 0, stream>>>(xb, xq, rowptr, csr, inv,
                                                        pS0, pN0, b0, h1, h1q, N_NODES);

    // layer 1: h2 = relu(h1@Ws1 + mean_fp8(h1q[nbr])@Wn1 + b1)
    gathergemm_k<false><<<gemmBlocks, b256, 0, stream>>>(h1, h1q, rowptr, csr, inv,
                                                         pS1, pN1, b1, h2, nullptr, N_NODES);

    // layer 2 (gemm-first, bf16 z): out = h2@Ws2 + b2 ; z = bf16(h2@Wn2) ; out += inv*segsum(z)
    dual64_k<<<gemmBlocks, b256, 0, stream>>>(h2, pN2, pS2, b2, z64, out, N_NODES);
    agg64_k<<<agg64Blocks, b256, 0, stream>>>(z64, rowptr, csr, inv, out, N_NODES);
}

// Round 18
// 205.834 us; speedup vs baseline: 1.0838x; 1.0838x over previous
//
#include <hip/hip_runtime.h>

#define N_NODES 50000
#define N_EDGES 800000
#define NB_SCAN 196        // total 256-chunks = 7*25 + 21
#define NODES_PER_GRP 6400 // chunk-aligned (25 chunks of 256); groups 0..7, last has 5200
#define CHUNKS_PER_GRP 25
#define BUCKET_CAP 131072  // per-bucket capacity (mean ~102400)
#define CAST_BLOCKS 6250   // blocks doing cast/zero in cast_pack_k

typedef unsigned short ushort_t;
typedef unsigned char  uchar_t;
typedef __attribute__((ext_vector_type(8))) short  short8v;   // 8 bf16 (4 VGPR) MFMA A/B frag
typedef __attribute__((ext_vector_type(4))) float  float4v;   // MFMA C/D frag
typedef __attribute__((ext_vector_type(2))) float  float2v;
typedef __attribute__((ext_vector_type(4))) unsigned short ushort4v;
typedef __attribute__((ext_vector_type(8))) unsigned short ushort8v;
typedef __attribute__((ext_vector_type(4))) int int4v;
typedef __attribute__((ext_vector_type(4))) unsigned char uchar4v;

#if defined(__has_builtin)
#if __has_builtin(__builtin_amdgcn_cvt_pk_f32_fp8)
#define HAVE_CVT_FP8 1
#endif
#endif

__device__ __forceinline__ ushort_t f2bf(float f) {
    unsigned u = __float_as_uint(f);
    unsigned r = 0x7fffu + ((u >> 16) & 1u);   // round-to-nearest-even
    return (ushort_t)((u + r) >> 16);
}
__device__ __forceinline__ float bf2f(ushort_t h) {
    return __uint_as_float((unsigned)h << 16);
}

// ---- OCP fp8 e4m3fn encode (epilogue-side, RNE via 2^-120 scaling trick) ----
__device__ __forceinline__ uchar_t f2fp8(float f) {
    float a = fminf(fabsf(f), 448.f);
    unsigned u = __float_as_uint(a * 0x1p-120f);   // e4m3 em field lands at bits 20..26
    u += 0x7FFFFu + ((u >> 20) & 1u);              // RNE at bit 20
    unsigned em = (u >> 20) & 0x7Fu;
    unsigned sgn = (__float_as_uint(f) >> 24) & 0x80u;
    return (uchar_t)(sgn | em);
}

#ifdef HAVE_CVT_FP8
// HW decode: v_cvt_pk_f32_fp8 converts 2 OCP-e4m3 bytes -> 2 f32 per instruction.
#define FP8_POSTSCALE 1.0f
__device__ __forceinline__ void acc8_fp8(float* a, uint2 q) {
    float2v p0 = __builtin_amdgcn_cvt_pk_f32_fp8(q.x, false);  // bytes 0,1
    float2v p1 = __builtin_amdgcn_cvt_pk_f32_fp8(q.x, true);   // bytes 2,3
    float2v p2 = __builtin_amdgcn_cvt_pk_f32_fp8(q.y, false);
    float2v p3 = __builtin_amdgcn_cvt_pk_f32_fp8(q.y, true);
    a[0] += p0[0]; a[1] += p0[1]; a[2] += p1[0]; a[3] += p1[1];
    a[4] += p2[0]; a[5] += p2[1]; a[6] += p3[0]; a[7] += p3[1];
}
#else
// SW fallback: branch-free decode, raw value = true_value * 2^-120 (folded into inv scale)
#define FP8_POSTSCALE 0x1p120f
#define DEC0(w) __uint_as_float((((w) << 24) & 0x80000000u) | (((w) << 20) & 0x07f00000u))
#define DEC1(w) __uint_as_float((((w) << 16) & 0x80000000u) | (((w) << 12) & 0x07f00000u))
#define DEC2(w) __uint_as_float((((w) <<  8) & 0x80000000u) | (((w) <<  4) & 0x07f00000u))
#define DEC3(w) __uint_as_float((((w)      ) & 0x80000000u) | (((w) >>  4) & 0x07f00000u))
__device__ __forceinline__ void acc8_fp8(float* a, uint2 q) {
    a[0] += DEC0(q.x); a[1] += DEC1(q.x); a[2] += DEC2(q.x); a[3] += DEC3(q.x);
    a[4] += DEC0(q.y); a[5] += DEC1(q.y); a[6] += DEC2(q.y); a[7] += DEC3(q.y);
}
#endif

// ---------------- fused: cast x->bf16+fp8 + zero bcur  |  pack weights ----------------
__global__ __launch_bounds__(256) void cast_pack_k(const float* __restrict__ x,
                                                   ushort_t* __restrict__ xb,
                                                   uchar_t* __restrict__ xq,
                                                   int* __restrict__ bcur,
                                                   const float* __restrict__ W0n, const float* __restrict__ W0s,
                                                   const float* __restrict__ W1n, const float* __restrict__ W1s,
                                                   const float* __restrict__ W2n, const float* __restrict__ W2s,
                                                   ushort_t* __restrict__ P) {
    const int b = blockIdx.x, t = threadIdx.x;
    if (b < CAST_BLOCKS) {
        int i = b * 256 + t;
        if (i < N_NODES * 32) {
            float4 v = ((const float4*)x)[i];
            ushort4v h;
            h[0] = f2bf(v.x); h[1] = f2bf(v.y); h[2] = f2bf(v.z); h[3] = f2bf(v.w);
            ((ushort4v*)xb)[i] = h;
            uchar4v q;
            q[0] = f2fp8(v.x); q[1] = f2fp8(v.y); q[2] = f2fp8(v.z); q[3] = f2fp8(v.w);
            ((uchar4v*)xq)[i] = q;
        }
        if (i < 8) bcur[i] = 0;
        return;
    }
    // weight packing: fp32 W[128][DOUT] -> bf16 MFMA B-fragment layout
    int tid = (b - CAST_BLOCKS) * 256 + t;   // 0..10239
    const float* W; int dout; int base; int r;
    if      (tid < 2048)  { W = W0n; dout = 128; base = 0;     r = tid; }
    else if (tid < 4096)  { W = W0s; dout = 128; base = 16384; r = tid - 2048; }
    else if (tid < 6144)  { W = W1n; dout = 128; base = 32768; r = tid - 4096; }
    else if (tid < 8192)  { W = W1s; dout = 128; base = 49152; r = tid - 6144; }
    else if (tid < 9216)  { W = W2n; dout = 64;  base = 65536; r = tid - 8192; }
    else                  { W = W2s; dout = 64;  base = 73728; r = tid - 9216; }
    int lane = r & 63;
    int ks = (r >> 6) & 3;
    int nt = r >> 8;
    int col = nt * 16 + (lane & 15);
    int k0 = ks * 32 + ((lane >> 4) << 3);
    ushort_t* d = P + (size_t)base + (size_t)r * 8;
    ushort4v lo4, hi4;
#pragma unroll
    for (int j = 0; j < 4; ++j) lo4[j] = f2bf(W[(size_t)(k0 + j) * dout + col]);
#pragma unroll
    for (int j = 0; j < 4; ++j) hi4[j] = f2bf(W[(size_t)(k0 + 4 + j) * dout + col]);
    *(ushort4v*)d = lo4;
    *(ushort4v*)(d + 4) = hi4;
}

// ---------------- edge bucketing: 782 blocks x 4 edges/thread ----------------
__global__ __launch_bounds__(256) void bucket_k(const int4v* __restrict__ dst4,
                                                const int4v* __restrict__ src4,
                                                int* __restrict__ bcur,
                                                int2* __restrict__ buckets) {
    __shared__ int lcount[8];
    __shared__ int lbase[8];
    const int t = threadIdx.x, b = blockIdx.x;
    if (t < 8) lcount[t] = 0;
    __syncthreads();

    const int idx = b * 256 + t;   // int4 index, n4 = 200000
    int4v d, s;
    if (idx < N_EDGES / 4) {
        d = __builtin_nontemporal_load(dst4 + idx);
        s = __builtin_nontemporal_load(src4 + idx);
    } else {
        d[0] = d[1] = d[2] = d[3] = -1;
        s[0] = s[1] = s[2] = s[3] = 0;
    }
    int g[4], li[4];
#pragma unroll
    for (int j = 0; j < 4; ++j) {
        int dv = d[j];
        g[j] = (dv >= 0) ? (dv / NODES_PER_GRP) : -1;
        li[j] = (g[j] >= 0) ? atomicAdd(&lcount[g[j]], 1) : 0;
    }
    __syncthreads();
    if (t < 8) lbase[t] = atomicAdd(bcur + t, lcount[t]);
    __syncthreads();
#pragma unroll
    for (int j = 0; j < 4; ++j) {
        if (g[j] >= 0) {
            int pos = lbase[g[j]] + li[j];
            buckets[(size_t)g[j] * BUCKET_CAP + pos] = make_int2(d[j], s[j]);
        }
    }
}

// ---------------- atomic-free degree + chunk sums ----------------
__global__ __launch_bounds__(1024) void deg_hist_k(const int* __restrict__ bcur,
                                                   const int2* __restrict__ buckets,
                                                   int* __restrict__ deg,
                                                   int* __restrict__ bsum) {
    __shared__ int hist[NODES_PER_GRP];
    const int g = blockIdx.x;
    const int t = threadIdx.x;
    const int lo = g * NODES_PER_GRP;
    const int cnt = bcur[g];
    const int2* bk = buckets + (size_t)g * BUCKET_CAP;
    for (int i = t; i < NODES_PER_GRP; i += 1024) hist[i] = 0;
    __syncthreads();
    for (int i = t; i < cnt; i += 1024) {
        atomicAdd(&hist[bk[i].x - lo], 1);
    }
    __syncthreads();
    const int nNodes = (N_NODES - lo < NODES_PER_GRP) ? (N_NODES - lo) : NODES_PER_GRP;
    for (int i = t; i < nNodes; i += 1024) deg[lo + i] = hist[i];
    const int wave = t >> 6, lane = t & 63;
    const int nch = (nNodes + 255) >> 8;
    for (int c = wave; c < nch; c += 16) {
        int base = c * 256 + lane;
        int s = hist[base] + hist[base + 64] + hist[base + 128] + hist[base + 192];
#pragma unroll
        for (int off = 32; off > 0; off >>= 1) s += __shfl_xor(s, off);
        if (lane == 0) bsum[g * CHUNKS_PER_GRP + c] = s;
    }
}

// ---------------- fused rowptr ----------------
__global__ __launch_bounds__(256) void rowptr_fused_k(const int* __restrict__ deg,
                                                      const int* __restrict__ bsum,
                                                      int* __restrict__ rowptr,
                                                      int* __restrict__ cursor,
                                                      float* __restrict__ inv) {
    __shared__ int sb[256];
    __shared__ int s[256];
    const int t = threadIdx.x, b = blockIdx.x;
    int v = (t < NB_SCAN) ? bsum[t] : 0;
    sb[t] = v;
    __syncthreads();
#pragma unroll
    for (int off = 1; off < 256; off <<= 1) {
        int u = (t >= off) ? sb[t - off] : 0;
        __syncthreads();
        sb[t] += u;
        __syncthreads();
    }
    const int boffb = (b == 0) ? 0 : sb[b - 1];
    if (b == NB_SCAN - 1 && t == 0) rowptr[N_NODES] = sb[NB_SCAN - 1];

    int i = b * 256 + t;
    int d = (i < N_NODES) ? deg[i] : 0;
    s[t] = d;
    __syncthreads();
#pragma unroll
    for (int off = 1; off < 256; off <<= 1) {
        int u = (t >= off) ? s[t - off] : 0;
        __syncthreads();
        s[t] += u;
        __syncthreads();
    }
    if (i < N_NODES) {
        int r = boffb + s[t] - d;
        rowptr[i] = r;
        cursor[i] = r;
        inv[i] = 1.0f / fmaxf((float)d, 1.0f);
    }
}

// ---------------- scatter from buckets ----------------
__global__ __launch_bounds__(256) void scatter_bucket_k(const int* __restrict__ bcur,
                                                        const int2* __restrict__ buckets,
                                                        int* __restrict__ cursor,
                                                        int* __restrict__ csr) {
    const int grp = blockIdx.x & 7;
    const int cnt = bcur[grp];
    const int2* bk = buckets + (size_t)grp * BUCKET_CAP;
    const int stride = (gridDim.x >> 3) * 256;
    for (int i = (blockIdx.x >> 3) * 256 + threadIdx.x; i < cnt; i += stride) {
        int2 e = bk[i];
        csr[atomicAdd(cursor + e.x, 1)] = e.y;
    }
}

// ---------------- FUSED fp8-gather-mean + dual-A GEMM ----------------
// Gather reads the fp8 shadow copy Hq (128 B/row); decode via HW v_cvt_pk_f32_fp8.
template <bool WQ>
__global__ __launch_bounds__(256, 4) void gathergemm_k(const ushort_t* __restrict__ H,
                                                       const uchar_t* __restrict__ Hq,
                                                       const int* __restrict__ rowptr,
                                                       const int* __restrict__ csr,
                                                       const float* __restrict__ inv,
                                                       const short8v* __restrict__ Ws,
                                                       const short8v* __restrict__ Wn,
                                                       const float* __restrict__ bias,
                                                       ushort_t* __restrict__ Out,
                                                       uchar_t* __restrict__ OutQ, int N) {
    __shared__ ushort_t sm[2][64 * 128];   // 2 x 16 KB
    char* sbH = (char*)sm[0];
    char* sbM = (char*)sm[1];
    const int bm = blockIdx.x * 64;
    const int t = threadIdx.x;
    const int w = t >> 6, l = t & 63;
    const ushort8v* Hp = (const ushort8v*)H;   // row stride 16 (256 B)
    const uint2* Qp = (const uint2*)Hq;        // row stride 16 (128 B)
    ushort8v zeroV = {0, 0, 0, 0, 0, 0, 0, 0};

    // stage H tile (swizzled)
#pragma unroll
    for (int it = 0; it < 4; ++it) {
        int r = it * 16 + (t >> 4);
        int row = bm + r;
        int byte = (r * 256 + (t & 15) * 16) ^ ((r & 7) << 4);
        ushort8v vh = zeroV;
        if (row < N) vh = Hp[(size_t)row * 16 + (t & 15)];
        *(ushort8v*)(sbH + byte) = vh;
    }

    // fp8 gather-mean M tile straight into swizzled LDS: 16 lanes per row, lane c owns cols [8c,8c+8)
    const int c = t & 15;
#pragma unroll
    for (int pass = 0; pass < 4; ++pass) {
        int r = pass * 16 + (t >> 4);
        int row = bm + r;
        int byte = (r * 256 + c * 16) ^ ((r & 7) << 4);
        ushort8v o = zeroV;
        if (row < N) {
            int start = rowptr[row], end = rowptr[row + 1];
            float a0[8] = {}, a1[8] = {}, a2[8] = {}, a3[8] = {};
            int j = start;
            for (; j + 3 < end; j += 4) {
                int u0 = csr[j], u1 = csr[j + 1], u2 = csr[j + 2], u3 = csr[j + 3];
                uint2 q0 = Qp[(size_t)u0 * 16 + c];
                uint2 q1 = Qp[(size_t)u1 * 16 + c];
                uint2 q2 = Qp[(size_t)u2 * 16 + c];
                uint2 q3 = Qp[(size_t)u3 * 16 + c];
                acc8_fp8(a0, q0); acc8_fp8(a1, q1);
                acc8_fp8(a2, q2); acc8_fp8(a3, q3);
            }
            for (; j < end; ++j) {
                uint2 q = Qp[(size_t)csr[j] * 16 + c];
                acc8_fp8(a0, q);
            }
            float scf = inv[row] * FP8_POSTSCALE;
#pragma unroll
            for (int k = 0; k < 8; ++k) o[k] = f2bf(((a0[k] + a1[k]) + (a2[k] + a3[k])) * scf);
        }
        *(ushort8v*)(sbM + byte) = o;
    }
    __syncthreads();

    float bv[8];
#pragma unroll
    for (int nt = 0; nt < 8; ++nt) bv[nt] = bias[nt * 16 + (l & 15)];

    float4v acc[8] = {};
#pragma unroll
    for (int ks = 0; ks < 4; ++ks) {
        int r0 = w * 16 + (l & 15);
        int b0 = (r0 * 256 + ks * 64 + (l >> 4) * 16) ^ ((r0 & 7) << 4);
        short8v ah = *(const short8v*)(sbH + b0);
        short8v am = *(const short8v*)(sbM + b0);
#pragma unroll
        for (int nt = 0; nt < 8; ++nt) {
            short8v bs = Ws[(nt * 4 + ks) * 64 + l];
            short8v bn = Wn[(nt * 4 + ks) * 64 + l];
            acc[nt] = __builtin_amdgcn_mfma_f32_16x16x32_bf16(ah, bs, acc[nt], 0, 0, 0);
            acc[nt] = __builtin_amdgcn_mfma_f32_16x16x32_bf16(am, bn, acc[nt], 0, 0, 0);
        }
    }

    // C/D layout: col = lane&15, row = (lane>>4)*4 + i  [verified m89]
#pragma unroll
    for (int i = 0; i < 4; ++i) {
        int row = bm + w * 16 + (l >> 4) * 4 + i;
        if (row < N) {
#pragma unroll
            for (int nt = 0; nt < 8; ++nt) {
                int col = nt * 16 + (l & 15);
                float v = fmaxf(acc[nt][i] + bv[nt], 0.f);
                Out[(size_t)row * 128 + col] = f2bf(v);
                if (WQ) OutQ[(size_t)row * 128 + col] = f2fp8(v);
            }
        }
    }
}

// ---------------- layer-2 dual GEMM: S(fp32,->out) = H@Wself + b ; Z(bf16) = H@Wneigh ----------------
__global__ __launch_bounds__(256, 4) void dual64_k(const ushort_t* __restrict__ A,
                                                   const short8v* __restrict__ Wn,
                                                   const short8v* __restrict__ Ws,
                                                   const float* __restrict__ bias,
                                                   ushort_t* __restrict__ Z,
                                                   float* __restrict__ S, int N) {
    constexpr int NT = 4;
    __shared__ ushort_t Asm[64 * 128];   // 16 KB
    char* sb = (char*)Asm;
    const int bm = blockIdx.x * 64;
    const int t = threadIdx.x;
    const int w = t >> 6, l = t & 63;

    {
        const ushort8v* Ap = (const ushort8v*)A;
        ushort8v zeroV = {0, 0, 0, 0, 0, 0, 0, 0};
#pragma unroll
        for (int it = 0; it < 4; ++it) {
            int r = it * 16 + (t >> 4);
            int row = bm + r;
            ushort8v v = zeroV;
            if (row < N) v = Ap[(size_t)row * 16 + (t & 15)];
            int byte = (r * 256 + (t & 15) * 16) ^ ((r & 7) << 4);
            *(ushort8v*)(sb + byte) = v;
        }
    }
    __syncthreads();

    float bv[NT];
#pragma unroll
    for (int nt = 0; nt < NT; ++nt) bv[nt] = bias[nt * 16 + (l & 15)];

    float4v accS[NT] = {}, accN[NT] = {};
#pragma unroll
    for (int ks = 0; ks < 4; ++ks) {
        int r0 = w * 16 + (l & 15);
        int b0 = (r0 * 256 + ks * 64 + (l >> 4) * 16) ^ ((r0 & 7) << 4);
        short8v a = *(const short8v*)(sb + b0);
#pragma unroll
        for (int nt = 0; nt < NT; ++nt) {
            short8v bs = Ws[(nt * 4 + ks) * 64 + l];
            short8v bn = Wn[(nt * 4 + ks) * 64 + l];
            accS[nt] = __builtin_amdgcn_mfma_f32_16x16x32_bf16(a, bs, accS[nt], 0, 0, 0);
            accN[nt] = __builtin_amdgcn_mfma_f32_16x16x32_bf16(a, bn, accN[nt], 0, 0, 0);
        }
    }

#pragma unroll
    for (int i = 0; i < 4; ++i) {
        int row = bm + w * 16 + (l >> 4) * 4 + i;
        if (row < N) {
#pragma unroll
            for (int nt = 0; nt < NT; ++nt) {
                int col = nt * 16 + (l & 15);
                S[(size_t)row * 64 + col] = accS[nt][i] + bv[nt];
                Z[(size_t)row * 64 + col] = f2bf(accN[nt][i]);
            }
        }
    }
}

// ---------------- layer-2 aggregation: out(fp32,=S) += inv * sum z[nbr]  (64-wide, bf16) ----------------
__global__ __launch_bounds__(256) void agg64_k(const ushort_t* __restrict__ z,
                                               const int* __restrict__ rowptr,
                                               const int* __restrict__ csr,
                                               const float* __restrict__ inv,
                                               float* __restrict__ out, int N) {
    int node = (blockIdx.x * 256 + threadIdx.x) >> 3;
    int c = threadIdx.x & 7;
    if (node >= N) return;
    int start = rowptr[node], end = rowptr[node + 1];

    const ushort8v* zp = (const ushort8v*)z;   // row stride 8 (128 B)
    float a0[8] = {}, a1[8] = {}, a2[8] = {}, a3[8] = {};
    int j = start;
    for (; j + 3 < end; j += 4) {
        int u0 = csr[j], u1 = csr[j + 1], u2 = csr[j + 2], u3 = csr[j + 3];
        ushort8v w0 = zp[(size_t)u0 * 8 + c];
        ushort8v w1 = zp[(size_t)u1 * 8 + c];
        ushort8v w2 = zp[(size_t)u2 * 8 + c];
        ushort8v w3 = zp[(size_t)u3 * 8 + c];
#pragma unroll
        for (int k = 0; k < 8; ++k) {
            a0[k] += bf2f(w0[k]); a1[k] += bf2f(w1[k]);
            a2[k] += bf2f(w2[k]); a3[k] += bf2f(w3[k]);
        }
    }
    for (; j < end; ++j) {
        ushort8v w = zp[(size_t)csr[j] * 8 + c];
#pragma unroll
        for (int k = 0; k < 8; ++k) a0[k] += bf2f(w[k]);
    }
    float s = inv[node];
    float* op = out + (size_t)node * 64 + c * 8;
    float4 o0 = *(float4*)op;
    float4 o1 = *(float4*)(op + 4);
    o0.x += ((a0[0] + a1[0]) + (a2[0] + a3[0])) * s;
    o0.y += ((a0[1] + a1[1]) + (a2[1] + a3[1])) * s;
    o0.z += ((a0[2] + a1[2]) + (a2[2] + a3[2])) * s;
    o0.w += ((a0[3] + a1[3]) + (a2[3] + a3[3])) * s;
    o1.x += ((a0[4] + a1[4]) + (a2[4] + a3[4])) * s;
    o1.y += ((a0[5] + a1[5]) + (a2[5] + a3[5])) * s;
    o1.z += ((a0[6] + a1[6]) + (a2[6] + a3[6])) * s;
    o1.w += ((a0[7] + a1[7]) + (a2[7] + a3[7])) * s;
    *(float4*)op = o0;
    *(float4*)(op + 4) = o1;
}

// ---------------- launch ----------------

extern "C" void kernel_launch(void* const* d_in, const int* in_sizes, int n_in,
                              void* d_out, int out_size, void* d_ws, size_t ws_size,
                              hipStream_t stream) {
    const float* x       = (const float*)d_in[0];
    const int*   src     = (const int*)d_in[1];
    const int*   dst     = (const int*)d_in[2];
    const float* Wself0  = (const float*)d_in[3];
    const float* Wneigh0 = (const float*)d_in[4];
    const float* b0      = (const float*)d_in[5];
    const float* Wself1  = (const float*)d_in[6];
    const float* Wneigh1 = (const float*)d_in[7];
    const float* b1      = (const float*)d_in[8];
    const float* Wself2  = (const float*)d_in[9];
    const float* Wneigh2 = (const float*)d_in[10];
    const float* b2      = (const float*)d_in[11];
    float* out = (float*)d_out;

    char* ws = (char*)d_ws;
    size_t off = 0;
    auto alloc = [&](size_t bytes) -> void* {
        void* p = ws + off;
        off += (bytes + 255) & ~(size_t)255;
        return p;
    };
    int*      deg     = (int*)alloc((size_t)N_NODES * 4);
    float*    inv     = (float*)alloc((size_t)N_NODES * 4);
    int*      rowptr  = (int*)alloc((size_t)(N_NODES + 1) * 4);
    int*      cursor  = (int*)alloc((size_t)N_NODES * 4);
    int*      csr     = (int*)alloc((size_t)N_EDGES * 4);
    int*      bsum    = (int*)alloc((size_t)NB_SCAN * 4);
    int*      bcur    = (int*)alloc((size_t)8 * 4);
    int2*     buckets = (int2*)alloc((size_t)8 * BUCKET_CAP * 8);
    ushort_t* packW   = (ushort_t*)alloc((size_t)81920 * 2);
    ushort_t* xb      = (ushort_t*)alloc((size_t)N_NODES * 128 * 2);
    uchar_t*  xq      = (uchar_t*)alloc((size_t)N_NODES * 128);
    ushort_t* h1      = (ushort_t*)alloc((size_t)N_NODES * 128 * 2);
    uchar_t*  h1q     = (uchar_t*)alloc((size_t)N_NODES * 128);
    ushort_t* h2      = (ushort_t*)alloc((size_t)N_NODES * 128 * 2);
    ushort_t* z64     = (ushort_t*)alloc((size_t)N_NODES * 64 * 2);

    dim3 b256(256);
    const int gemmBlocks   = (N_NODES + 63) / 64;          // 782 (64-row tiles, 4 blocks/CU)
    const int agg64Blocks  = (N_NODES * 8 + 255) / 256;    // 1563
    const int bucketBlocks = (N_EDGES / 4 + 255) / 256;    // 782 (4 edges/thread)

    // ---- CSR build: cast+pack | bucket | LDS-hist deg+chunk-sums | rowptr | scatter ----
    cast_pack_k<<<CAST_BLOCKS + 40, b256, 0, stream>>>(x, xb, xq, bcur,
                                                       Wneigh0, Wself0, Wneigh1, Wself1,
                                                       Wneigh2, Wself2, packW);
    bucket_k<<<bucketBlocks, b256, 0, stream>>>((const int4v*)dst, (const int4v*)src,
                                                bcur, buckets);
    deg_hist_k<<<8, dim3(1024), 0, stream>>>(bcur, buckets, deg, bsum);
    rowptr_fused_k<<<NB_SCAN, b256, 0, stream>>>(deg, bsum, rowptr, cursor, inv);
    scatter_bucket_k<<<512, b256, 0, stream>>>(bcur, buckets, cursor, csr);

    const short8v* pN0 = (const short8v*)(packW);
    const short8v* pS0 = (const short8v*)(packW + 16384);
    const short8v* pN1 = (const short8v*)(packW + 32768);
    const short8v* pS1 = (const short8v*)(packW + 49152);
    const short8v* pN2 = (const short8v*)(packW + 65536);
    const short8v* pS2 = (const short8v*)(packW + 73728);

    // layer 0: h1 = relu(xb@Ws0 + mean_fp8(xq[nbr])@Wn0 + b0); also writes h1q (fp8 shadow)
    gathergemm_k<true><<<gemmBlocks, b256, 0, stream>>>(xb, xq, rowptr, csr, inv,
                                                        pS0, pN0, b0, h1, h1q, N_NODES);

    // layer 1: h2 = relu(h1@Ws1 + mean_fp8(h1q[nbr])@Wn1 + b1)
    gathergemm_k<false><<<gemmBlocks, b256, 0, stream>>>(h1, h1q, rowptr, csr, inv,
                                                         pS1, pN1, b1, h2, nullptr, N_NODES);

    // layer 2 (gemm-first, bf16 z): out = h2@Ws2 + b2 ; z = bf16(h2@Wn2) ; out += inv*segsum(z)
    dual64_k<<<gemmBlocks, b256, 0, stream>>>(h2, pN2, pS2, b2, z64, out, N_NODES);
    agg64_k<<<agg64Blocks, b256, 0, stream>>>(z64, rowptr, csr, inv, out, N_NODES);
}

// Round 19
// 200.493 us; speedup vs baseline: 1.1127x; 1.0266x over previous
//
#include <hip/hip_runtime.h>

#define N_NODES 50000
#define N_EDGES 800000
#define NB_SCAN 196        // total 256-chunks = 7*25 + 21
#define NODES_PER_GRP 6400 // chunk-aligned (25 chunks of 256); groups 0..7, last has 5200
#define CHUNKS_PER_GRP 25
#define BUCKET_CAP 131072  // per-bucket capacity (mean ~102400)
#define CAST_BLOCKS 6250   // blocks doing cast/zero in cast_pack_k

typedef unsigned short ushort_t;
typedef unsigned char  uchar_t;
typedef __attribute__((ext_vector_type(8))) short  short8v;   // 8 bf16 (4 VGPR) MFMA A/B frag
typedef __attribute__((ext_vector_type(4))) float  float4v;   // MFMA C/D frag
typedef __attribute__((ext_vector_type(2))) float  float2v;
typedef __attribute__((ext_vector_type(4))) unsigned short ushort4v;
typedef __attribute__((ext_vector_type(8))) unsigned short ushort8v;
typedef __attribute__((ext_vector_type(4))) int int4v;
typedef __attribute__((ext_vector_type(4))) unsigned char uchar4v;

#if defined(__has_builtin)
#if __has_builtin(__builtin_amdgcn_cvt_pk_f32_fp8)
#define HAVE_CVT_FP8 1
#endif
#endif

__device__ __forceinline__ ushort_t f2bf(float f) {
    unsigned u = __float_as_uint(f);
    unsigned r = 0x7fffu + ((u >> 16) & 1u);   // round-to-nearest-even
    return (ushort_t)((u + r) >> 16);
}
__device__ __forceinline__ float bf2f(ushort_t h) {
    return __uint_as_float((unsigned)h << 16);
}

// ---- OCP fp8 e4m3fn encode (epilogue-side, RNE via 2^-120 scaling trick) ----
__device__ __forceinline__ uchar_t f2fp8(float f) {
    float a = fminf(fabsf(f), 448.f);
    unsigned u = __float_as_uint(a * 0x1p-120f);   // e4m3 em field lands at bits 20..26
    u += 0x7FFFFu + ((u >> 20) & 1u);              // RNE at bit 20
    unsigned em = (u >> 20) & 0x7Fu;
    unsigned sgn = (__float_as_uint(f) >> 24) & 0x80u;
    return (uchar_t)(sgn | em);
}

#ifdef HAVE_CVT_FP8
// HW decode: v_cvt_pk_f32_fp8 converts 2 OCP-e4m3 bytes -> 2 f32 per instruction.
#define FP8_POSTSCALE 1.0f
__device__ __forceinline__ void acc8_fp8(float* a, uint2 q) {
    float2v p0 = __builtin_amdgcn_cvt_pk_f32_fp8(q.x, false);  // bytes 0,1
    float2v p1 = __builtin_amdgcn_cvt_pk_f32_fp8(q.x, true);   // bytes 2,3
    float2v p2 = __builtin_amdgcn_cvt_pk_f32_fp8(q.y, false);
    float2v p3 = __builtin_amdgcn_cvt_pk_f32_fp8(q.y, true);
    a[0] += p0[0]; a[1] += p0[1]; a[2] += p1[0]; a[3] += p1[1];
    a[4] += p2[0]; a[5] += p2[1]; a[6] += p3[0]; a[7] += p3[1];
}
#else
// SW fallback: branch-free decode, raw value = true_value * 2^-120 (folded into inv scale)
#define FP8_POSTSCALE 0x1p120f
#define DEC0(w) __uint_as_float((((w) << 24) & 0x80000000u) | (((w) << 20) & 0x07f00000u))
#define DEC1(w) __uint_as_float((((w) << 16) & 0x80000000u) | (((w) << 12) & 0x07f00000u))
#define DEC2(w) __uint_as_float((((w) <<  8) & 0x80000000u) | (((w) <<  4) & 0x07f00000u))
#define DEC3(w) __uint_as_float((((w)      ) & 0x80000000u) | (((w) >>  4) & 0x07f00000u))
__device__ __forceinline__ void acc8_fp8(float* a, uint2 q) {
    a[0] += DEC0(q.x); a[1] += DEC1(q.x); a[2] += DEC2(q.x); a[3] += DEC3(q.x);
    a[4] += DEC0(q.y); a[5] += DEC1(q.y); a[6] += DEC2(q.y); a[7] += DEC3(q.y);
}
#endif

// ---------------- fused: cast x->bf16+fp8 + zero bcur  |  pack weights ----------------
__global__ __launch_bounds__(256) void cast_pack_k(const float* __restrict__ x,
                                                   ushort_t* __restrict__ xb,
                                                   uchar_t* __restrict__ xq,
                                                   int* __restrict__ bcur,
                                                   const float* __restrict__ W0n, const float* __restrict__ W0s,
                                                   const float* __restrict__ W1n, const float* __restrict__ W1s,
                                                   const float* __restrict__ W2n, const float* __restrict__ W2s,
                                                   ushort_t* __restrict__ P) {
    const int b = blockIdx.x, t = threadIdx.x;
    if (b < CAST_BLOCKS) {
        int i = b * 256 + t;
        if (i < N_NODES * 32) {
            float4 v = ((const float4*)x)[i];
            ushort4v h;
            h[0] = f2bf(v.x); h[1] = f2bf(v.y); h[2] = f2bf(v.z); h[3] = f2bf(v.w);
            ((ushort4v*)xb)[i] = h;
            uchar4v q;
            q[0] = f2fp8(v.x); q[1] = f2fp8(v.y); q[2] = f2fp8(v.z); q[3] = f2fp8(v.w);
            ((uchar4v*)xq)[i] = q;
        }
        if (i < 8) bcur[i] = 0;
        return;
    }
    // weight packing: fp32 W[128][DOUT] -> bf16 MFMA B-fragment layout
    int tid = (b - CAST_BLOCKS) * 256 + t;   // 0..10239
    const float* W; int dout; int base; int r;
    if      (tid < 2048)  { W = W0n; dout = 128; base = 0;     r = tid; }
    else if (tid < 4096)  { W = W0s; dout = 128; base = 16384; r = tid - 2048; }
    else if (tid < 6144)  { W = W1n; dout = 128; base = 32768; r = tid - 4096; }
    else if (tid < 8192)  { W = W1s; dout = 128; base = 49152; r = tid - 6144; }
    else if (tid < 9216)  { W = W2n; dout = 64;  base = 65536; r = tid - 8192; }
    else                  { W = W2s; dout = 64;  base = 73728; r = tid - 9216; }
    int lane = r & 63;
    int ks = (r >> 6) & 3;
    int nt = r >> 8;
    int col = nt * 16 + (lane & 15);
    int k0 = ks * 32 + ((lane >> 4) << 3);
    ushort_t* d = P + (size_t)base + (size_t)r * 8;
    ushort4v lo4, hi4;
#pragma unroll
    for (int j = 0; j < 4; ++j) lo4[j] = f2bf(W[(size_t)(k0 + j) * dout + col]);
#pragma unroll
    for (int j = 0; j < 4; ++j) hi4[j] = f2bf(W[(size_t)(k0 + 4 + j) * dout + col]);
    *(ushort4v*)d = lo4;
    *(ushort4v*)(d + 4) = hi4;
}

// ---------------- edge bucketing: 782 blocks x 4 edges/thread ----------------
__global__ __launch_bounds__(256) void bucket_k(const int4v* __restrict__ dst4,
                                                const int4v* __restrict__ src4,
                                                int* __restrict__ bcur,
                                                int2* __restrict__ buckets) {
    __shared__ int lcount[8];
    __shared__ int lbase[8];
    const int t = threadIdx.x, b = blockIdx.x;
    if (t < 8) lcount[t] = 0;
    __syncthreads();

    const int idx = b * 256 + t;   // int4 index, n4 = 200000
    int4v d, s;
    if (idx < N_EDGES / 4) {
        d = __builtin_nontemporal_load(dst4 + idx);
        s = __builtin_nontemporal_load(src4 + idx);
    } else {
        d[0] = d[1] = d[2] = d[3] = -1;
        s[0] = s[1] = s[2] = s[3] = 0;
    }
    int g[4], li[4];
#pragma unroll
    for (int j = 0; j < 4; ++j) {
        int dv = d[j];
        g[j] = (dv >= 0) ? (dv / NODES_PER_GRP) : -1;
        li[j] = (g[j] >= 0) ? atomicAdd(&lcount[g[j]], 1) : 0;
    }
    __syncthreads();
    if (t < 8) lbase[t] = atomicAdd(bcur + t, lcount[t]);
    __syncthreads();
#pragma unroll
    for (int j = 0; j < 4; ++j) {
        if (g[j] >= 0) {
            int pos = lbase[g[j]] + li[j];
            buckets[(size_t)g[j] * BUCKET_CAP + pos] = make_int2(d[j], s[j]);
        }
    }
}

// ---------------- atomic-free degree + chunk sums ----------------
__global__ __launch_bounds__(1024) void deg_hist_k(const int* __restrict__ bcur,
                                                   const int2* __restrict__ buckets,
                                                   int* __restrict__ deg,
                                                   int* __restrict__ bsum) {
    __shared__ int hist[NODES_PER_GRP];
    const int g = blockIdx.x;
    const int t = threadIdx.x;
    const int lo = g * NODES_PER_GRP;
    const int cnt = bcur[g];
    const int2* bk = buckets + (size_t)g * BUCKET_CAP;
    for (int i = t; i < NODES_PER_GRP; i += 1024) hist[i] = 0;
    __syncthreads();
    for (int i = t; i < cnt; i += 1024) {
        atomicAdd(&hist[bk[i].x - lo], 1);
    }
    __syncthreads();
    const int nNodes = (N_NODES - lo < NODES_PER_GRP) ? (N_NODES - lo) : NODES_PER_GRP;
    for (int i = t; i < nNodes; i += 1024) deg[lo + i] = hist[i];
    const int wave = t >> 6, lane = t & 63;
    const int nch = (nNodes + 255) >> 8;
    for (int c = wave; c < nch; c += 16) {
        int base = c * 256 + lane;
        int s = hist[base] + hist[base + 64] + hist[base + 128] + hist[base + 192];
#pragma unroll
        for (int off = 32; off > 0; off >>= 1) s += __shfl_xor(s, off);
        if (lane == 0) bsum[g * CHUNKS_PER_GRP + c] = s;
    }
}

// ---------------- fused rowptr ----------------
__global__ __launch_bounds__(256) void rowptr_fused_k(const int* __restrict__ deg,
                                                      const int* __restrict__ bsum,
                                                      int* __restrict__ rowptr,
                                                      int* __restrict__ cursor,
                                                      float* __restrict__ inv) {
    __shared__ int sb[256];
    __shared__ int s[256];
    const int t = threadIdx.x, b = blockIdx.x;
    int v = (t < NB_SCAN) ? bsum[t] : 0;
    sb[t] = v;
    __syncthreads();
#pragma unroll
    for (int off = 1; off < 256; off <<= 1) {
        int u = (t >= off) ? sb[t - off] : 0;
        __syncthreads();
        sb[t] += u;
        __syncthreads();
    }
    const int boffb = (b == 0) ? 0 : sb[b - 1];
    if (b == NB_SCAN - 1 && t == 0) rowptr[N_NODES] = sb[NB_SCAN - 1];

    int i = b * 256 + t;
    int d = (i < N_NODES) ? deg[i] : 0;
    s[t] = d;
    __syncthreads();
#pragma unroll
    for (int off = 1; off < 256; off <<= 1) {
        int u = (t >= off) ? s[t - off] : 0;
        __syncthreads();
        s[t] += u;
        __syncthreads();
    }
    if (i < N_NODES) {
        int r = boffb + s[t] - d;
        rowptr[i] = r;
        cursor[i] = r;
        inv[i] = 1.0f / fmaxf((float)d, 1.0f);
    }
}

// ---------------- scatter from buckets ----------------
__global__ __launch_bounds__(256) void scatter_bucket_k(const int* __restrict__ bcur,
                                                        const int2* __restrict__ buckets,
                                                        int* __restrict__ cursor,
                                                        int* __restrict__ csr) {
    const int grp = blockIdx.x & 7;
    const int cnt = bcur[grp];
    const int2* bk = buckets + (size_t)grp * BUCKET_CAP;
    const int stride = (gridDim.x >> 3) * 256;
    for (int i = (blockIdx.x >> 3) * 256 + threadIdx.x; i < cnt; i += stride) {
        int2 e = bk[i];
        csr[atomicAdd(cursor + e.x, 1)] = e.y;
    }
}

// ---------------- FUSED fp8-gather-mean + dual-A GEMM ----------------
// Gather reads the fp8 shadow copy Hq (128 B/row); decode via HW v_cvt_pk_f32_fp8;
// 8-deep edge unroll (8 independent row loads in flight per thread).
template <bool WQ>
__global__ __launch_bounds__(256, 4) void gathergemm_k(const ushort_t* __restrict__ H,
                                                       const uchar_t* __restrict__ Hq,
                                                       const int* __restrict__ rowptr,
                                                       const int* __restrict__ csr,
                                                       const float* __restrict__ inv,
                                                       const short8v* __restrict__ Ws,
                                                       const short8v* __restrict__ Wn,
                                                       const float* __restrict__ bias,
                                                       ushort_t* __restrict__ Out,
                                                       uchar_t* __restrict__ OutQ, int N) {
    __shared__ ushort_t sm[2][64 * 128];   // 2 x 16 KB
    char* sbH = (char*)sm[0];
    char* sbM = (char*)sm[1];
    const int bm = blockIdx.x * 64;
    const int t = threadIdx.x;
    const int w = t >> 6, l = t & 63;
    const ushort8v* Hp = (const ushort8v*)H;   // row stride 16 (256 B)
    const uint2* Qp = (const uint2*)Hq;        // row stride 16 (128 B)
    ushort8v zeroV = {0, 0, 0, 0, 0, 0, 0, 0};

    // stage H tile (swizzled)
#pragma unroll
    for (int it = 0; it < 4; ++it) {
        int r = it * 16 + (t >> 4);
        int row = bm + r;
        int byte = (r * 256 + (t & 15) * 16) ^ ((r & 7) << 4);
        ushort8v vh = zeroV;
        if (row < N) vh = Hp[(size_t)row * 16 + (t & 15)];
        *(ushort8v*)(sbH + byte) = vh;
    }

    // fp8 gather-mean M tile straight into swizzled LDS: 16 lanes per row, lane c owns cols [8c,8c+8)
    const int c = t & 15;
#pragma unroll
    for (int pass = 0; pass < 4; ++pass) {
        int r = pass * 16 + (t >> 4);
        int row = bm + r;
        int byte = (r * 256 + c * 16) ^ ((r & 7) << 4);
        ushort8v o = zeroV;
        if (row < N) {
            int start = rowptr[row], end = rowptr[row + 1];
            float a0[8] = {}, a1[8] = {}, a2[8] = {}, a3[8] = {};
            int j = start;
            for (; j + 7 < end; j += 8) {   // 8 loads in flight
                int u0 = csr[j],     u1 = csr[j + 1], u2 = csr[j + 2], u3 = csr[j + 3];
                int u4 = csr[j + 4], u5 = csr[j + 5], u6 = csr[j + 6], u7 = csr[j + 7];
                uint2 q0 = Qp[(size_t)u0 * 16 + c];
                uint2 q1 = Qp[(size_t)u1 * 16 + c];
                uint2 q2 = Qp[(size_t)u2 * 16 + c];
                uint2 q3 = Qp[(size_t)u3 * 16 + c];
                uint2 q4 = Qp[(size_t)u4 * 16 + c];
                uint2 q5 = Qp[(size_t)u5 * 16 + c];
                uint2 q6 = Qp[(size_t)u6 * 16 + c];
                uint2 q7 = Qp[(size_t)u7 * 16 + c];
                acc8_fp8(a0, q0); acc8_fp8(a1, q1);
                acc8_fp8(a2, q2); acc8_fp8(a3, q3);
                acc8_fp8(a0, q4); acc8_fp8(a1, q5);
                acc8_fp8(a2, q6); acc8_fp8(a3, q7);
            }
            for (; j + 3 < end; j += 4) {
                int u0 = csr[j], u1 = csr[j + 1], u2 = csr[j + 2], u3 = csr[j + 3];
                uint2 q0 = Qp[(size_t)u0 * 16 + c];
                uint2 q1 = Qp[(size_t)u1 * 16 + c];
                uint2 q2 = Qp[(size_t)u2 * 16 + c];
                uint2 q3 = Qp[(size_t)u3 * 16 + c];
                acc8_fp8(a0, q0); acc8_fp8(a1, q1);
                acc8_fp8(a2, q2); acc8_fp8(a3, q3);
            }
            for (; j < end; ++j) {
                uint2 q = Qp[(size_t)csr[j] * 16 + c];
                acc8_fp8(a0, q);
            }
            float scf = inv[row] * FP8_POSTSCALE;
#pragma unroll
            for (int k = 0; k < 8; ++k) o[k] = f2bf(((a0[k] + a1[k]) + (a2[k] + a3[k])) * scf);
        }
        *(ushort8v*)(sbM + byte) = o;
    }
    __syncthreads();

    float bv[8];
#pragma unroll
    for (int nt = 0; nt < 8; ++nt) bv[nt] = bias[nt * 16 + (l & 15)];

    float4v acc[8] = {};
#pragma unroll
    for (int ks = 0; ks < 4; ++ks) {
        int r0 = w * 16 + (l & 15);
        int b0 = (r0 * 256 + ks * 64 + (l >> 4) * 16) ^ ((r0 & 7) << 4);
        short8v ah = *(const short8v*)(sbH + b0);
        short8v am = *(const short8v*)(sbM + b0);
#pragma unroll
        for (int nt = 0; nt < 8; ++nt) {
            short8v bs = Ws[(nt * 4 + ks) * 64 + l];
            short8v bn = Wn[(nt * 4 + ks) * 64 + l];
            acc[nt] = __builtin_amdgcn_mfma_f32_16x16x32_bf16(ah, bs, acc[nt], 0, 0, 0);
            acc[nt] = __builtin_amdgcn_mfma_f32_16x16x32_bf16(am, bn, acc[nt], 0, 0, 0);
        }
    }

    // C/D layout: col = lane&15, row = (lane>>4)*4 + i  [verified m89]
#pragma unroll
    for (int i = 0; i < 4; ++i) {
        int row = bm + w * 16 + (l >> 4) * 4 + i;
        if (row < N) {
#pragma unroll
            for (int nt = 0; nt < 8; ++nt) {
                int col = nt * 16 + (l & 15);
                float v = fmaxf(acc[nt][i] + bv[nt], 0.f);
                Out[(size_t)row * 128 + col] = f2bf(v);
                if (WQ) OutQ[(size_t)row * 128 + col] = f2fp8(v);
            }
        }
    }
}

// ---------------- layer-2 dual GEMM: S(fp32,->out) = H@Wself + b ; Z(bf16) = H@Wneigh ----------------
__global__ __launch_bounds__(256, 4) void dual64_k(const ushort_t* __restrict__ A,
                                                   const short8v* __restrict__ Wn,
                                                   const short8v* __restrict__ Ws,
                                                   const float* __restrict__ bias,
                                                   ushort_t* __restrict__ Z,
                                                   float* __restrict__ S, int N) {
    constexpr int NT = 4;
    __shared__ ushort_t Asm[64 * 128];   // 16 KB
    char* sb = (char*)Asm;
    const int bm = blockIdx.x * 64;
    const int t = threadIdx.x;
    const int w = t >> 6, l = t & 63;

    {
        const ushort8v* Ap = (const ushort8v*)A;
        ushort8v zeroV = {0, 0, 0, 0, 0, 0, 0, 0};
#pragma unroll
        for (int it = 0; it < 4; ++it) {
            int r = it * 16 + (t >> 4);
            int row = bm + r;
            ushort8v v = zeroV;
            if (row < N) v = Ap[(size_t)row * 16 + (t & 15)];
            int byte = (r * 256 + (t & 15) * 16) ^ ((r & 7) << 4);
            *(ushort8v*)(sb + byte) = v;
        }
    }
    __syncthreads();

    float bv[NT];
#pragma unroll
    for (int nt = 0; nt < NT; ++nt) bv[nt] = bias[nt * 16 + (l & 15)];

    float4v accS[NT] = {}, accN[NT] = {};
#pragma unroll
    for (int ks = 0; ks < 4; ++ks) {
        int r0 = w * 16 + (l & 15);
        int b0 = (r0 * 256 + ks * 64 + (l >> 4) * 16) ^ ((r0 & 7) << 4);
        short8v a = *(const short8v*)(sb + b0);
#pragma unroll
        for (int nt = 0; nt < NT; ++nt) {
            short8v bs = Ws[(nt * 4 + ks) * 64 + l];
            short8v bn = Wn[(nt * 4 + ks) * 64 + l];
            accS[nt] = __builtin_amdgcn_mfma_f32_16x16x32_bf16(a, bs, accS[nt], 0, 0, 0);
            accN[nt] = __builtin_amdgcn_mfma_f32_16x16x32_bf16(a, bn, accN[nt], 0, 0, 0);
        }
    }

#pragma unroll
    for (int i = 0; i < 4; ++i) {
        int row = bm + w * 16 + (l >> 4) * 4 + i;
        if (row < N) {
#pragma unroll
            for (int nt = 0; nt < NT; ++nt) {
                int col = nt * 16 + (l & 15);
                S[(size_t)row * 64 + col] = accS[nt][i] + bv[nt];
                Z[(size_t)row * 64 + col] = f2bf(accN[nt][i]);
            }
        }
    }
}

// ---------------- layer-2 aggregation: out(fp32,=S) += inv * sum z[nbr]  (64-wide, bf16) ----------------
__global__ __launch_bounds__(256) void agg64_k(const ushort_t* __restrict__ z,
                                               const int* __restrict__ rowptr,
                                               const int* __restrict__ csr,
                                               const float* __restrict__ inv,
                                               float* __restrict__ out, int N) {
    int node = (blockIdx.x * 256 + threadIdx.x) >> 3;
    int c = threadIdx.x & 7;
    if (node >= N) return;
    int start = rowptr[node], end = rowptr[node + 1];

    const ushort8v* zp = (const ushort8v*)z;   // row stride 8 (128 B)
    float a0[8] = {}, a1[8] = {}, a2[8] = {}, a3[8] = {};
    int j = start;
    for (; j + 3 < end; j += 4) {
        int u0 = csr[j], u1 = csr[j + 1], u2 = csr[j + 2], u3 = csr[j + 3];
        ushort8v w0 = zp[(size_t)u0 * 8 + c];
        ushort8v w1 = zp[(size_t)u1 * 8 + c];
        ushort8v w2 = zp[(size_t)u2 * 8 + c];
        ushort8v w3 = zp[(size_t)u3 * 8 + c];
#pragma unroll
    for (int k = 0; k < 8; ++k) {
            a0[k] += bf2f(w0[k]); a1[k] += bf2f(w1[k]);
            a2[k] += bf2f(w2[k]); a3[k] += bf2f(w3[k]);
        }
    }
    for (; j < end; ++j) {
        ushort8v w = zp[(size_t)csr[j] * 8 + c];
#pragma unroll
        for (int k = 0; k < 8; ++k) a0[k] += bf2f(w[k]);
    }
    float s = inv[node];
    float* op = out + (size_t)node * 64 + c * 8;
    float4 o0 = *(float4*)op;
    float4 o1 = *(float4*)(op + 4);
    o0.x += ((a0[0] + a1[0]) + (a2[0] + a3[0])) * s;
    o0.y += ((a0[1] + a1[1]) + (a2[1] + a3[1])) * s;
    o0.z += ((a0[2] + a1[2]) + (a2[2] + a3[2])) * s;
    o0.w += ((a0[3] + a1[3]) + (a2[3] + a3[3])) * s;
    o1.x += ((a0[4] + a1[4]) + (a2[4] + a3[4])) * s;
    o1.y += ((a0[5] + a1[5]) + (a2[5] + a3[5])) * s;
    o1.z += ((a0[6] + a1[6]) + (a2[6] + a3[6])) * s;
    o1.w += ((a0[7] + a1[7]) + (a2[7] + a3[7])) * s;
    *(float4*)op = o0;
    *(float4*)(op + 4) = o1;
}

// ---------------- launch ----------------

extern "C" void kernel_launch(void* const* d_in, const int* in_sizes, int n_in,
                              void* d_out, int out_size, void* d_ws, size_t ws_size,
                              hipStream_t stream) {
    const float* x       = (const float*)d_in[0];
    const int*   src     = (const int*)d_in[1];
    const int*   dst     = (const int*)d_in[2];
    const float* Wself0  = (const float*)d_in[3];
    const float* Wneigh0 = (const float*)d_in[4];
    const float* b0      = (const float*)d_in[5];
    const float* Wself1  = (const float*)d_in[6];
    const float* Wneigh1 = (const float*)d_in[7];
    const float* b1      = (const float*)d_in[8];
    const float* Wself2  = (const float*)d_in[9];
    const float* Wneigh2 = (const float*)d_in[10];
    const float* b2      = (const float*)d_in[11];
    float* out = (float*)d_out;

    char* ws = (char*)d_ws;
    size_t off = 0;
    auto alloc = [&](size_t bytes) -> void* {
        void* p = ws + off;
        off += (bytes + 255) & ~(size_t)255;
        return p;
    };
    int*      deg     = (int*)alloc((size_t)N_NODES * 4);
    float*    inv     = (float*)alloc((size_t)N_NODES * 4);
    int*      rowptr  = (int*)alloc((size_t)(N_NODES + 1) * 4);
    int*      cursor  = (int*)alloc((size_t)N_NODES * 4);
    int*      csr     = (int*)alloc((size_t)N_EDGES * 4);
    int*      bsum    = (int*)alloc((size_t)NB_SCAN * 4);
    int*      bcur    = (int*)alloc((size_t)8 * 4);
    int2*     buckets = (int2*)alloc((size_t)8 * BUCKET_CAP * 8);
    ushort_t* packW   = (ushort_t*)alloc((size_t)81920 * 2);
    ushort_t* xb      = (ushort_t*)alloc((size_t)N_NODES * 128 * 2);
    uchar_t*  xq      = (uchar_t*)alloc((size_t)N_NODES * 128);
    ushort_t* h1      = (ushort_t*)alloc((size_t)N_NODES * 128 * 2);
    uchar_t*  h1q     = (uchar_t*)alloc((size_t)N_NODES * 128);
    ushort_t* h2      = (ushort_t*)alloc((size_t)N_NODES * 128 * 2);
    ushort_t* z64     = (ushort_t*)alloc((size_t)N_NODES * 64 * 2);

    dim3 b256(256);
    const int gemmBlocks   = (N_NODES + 63) / 64;          // 782 (64-row tiles, 4 blocks/CU)
    const int agg64Blocks  = (N_NODES * 8 + 255) / 256;    // 1563
    const int bucketBlocks = (N_EDGES / 4 + 255) / 256;    // 782 (4 edges/thread)

    // ---- CSR build: cast+pack | bucket | LDS-hist deg+chunk-sums | rowptr | scatter ----
    cast_pack_k<<<CAST_BLOCKS + 40, b256, 0, stream>>>(x, xb, xq, bcur,
                                                       Wneigh0, Wself0, Wneigh1, Wself1,
                                                       Wneigh2, Wself2, packW);
    bucket_k<<<bucketBlocks, b256, 0, stream>>>((const int4v*)dst, (const int4v*)src,
                                                bcur, buckets);
    deg_hist_k<<<8, dim3(1024), 0, stream>>>(bcur, buckets, deg, bsum);
    rowptr_fused_k<<<NB_SCAN, b256, 0, stream>>>(deg, bsum, rowptr, cursor, inv);
    scatter_bucket_k<<<512, b256, 0, stream>>>(bcur, buckets, cursor, csr);

    const short8v* pN0 = (const short8v*)(packW);
    const short8v* pS0 = (const short8v*)(packW + 16384);
    const short8v* pN1 = (const short8v*)(packW + 32768);
    const short8v* pS1 = (const short8v*)(packW + 49152);
    const short8v* pN2 = (const short8v*)(packW + 65536);
    const short8v* pS2 = (const short8v*)(packW + 73728);

    // layer 0: h1 = relu(xb@Ws0 + mean_fp8(xq[nbr])@Wn0 + b0); also writes h1q (fp8 shadow)
    gathergemm_k<true><<<gemmBlocks, b256, 0, stream>>>(xb, xq, rowptr, csr, inv,
                                                        pS0, pN0, b0, h1, h1q, N_NODES);

    // layer 1: h2 = relu(h1@Ws1 + mean_fp8(h1q[nbr])@Wn1 + b1)
    gathergemm_k<false><<<gemmBlocks, b256, 0, stream>>>(h1, h1q, rowptr, csr, inv,
                                                         pS1, pN1, b1, h2, nullptr, N_NODES);

    // layer 2 (gemm-first, bf16 z): out = h2@Ws2 + b2 ; z = bf16(h2@Wn2) ; out += inv*segsum(z)
    dual64_k<<<gemmBlocks, b256, 0, stream>>>(h2, pN2, pS2, b2, z64, out, N_NODES);
    agg64_k<<<agg64Blocks, b256, 0, stream>>>(z64, rowptr, csr, inv, out, N_NODES);
}

// Round 20
// 196.603 us; speedup vs baseline: 1.1347x; 1.0198x over previous
//
#include <hip/hip_runtime.h>

#define N_NODES 50000
#define N_EDGES 800000
#define NB_SCAN 196        // total 256-chunks = 7*25 + 21
#define NODES_PER_GRP 6400 // chunk-aligned (25 chunks of 256); groups 0..7, last has 5200
#define CHUNKS_PER_GRP 25
#define BUCKET_CAP 131072  // per-bucket capacity (mean ~102400)
#define CAST_BLOCKS 6250   // blocks doing cast/zero in cast_pack_k

typedef unsigned short ushort_t;
typedef unsigned char  uchar_t;
typedef __attribute__((ext_vector_type(8))) short  short8v;   // 8 bf16 (4 VGPR) MFMA A/B frag
typedef __attribute__((ext_vector_type(4))) float  float4v;   // MFMA C/D frag
typedef __attribute__((ext_vector_type(2))) float  float2v;
typedef __attribute__((ext_vector_type(4))) unsigned short ushort4v;
typedef __attribute__((ext_vector_type(8))) unsigned short ushort8v;
typedef __attribute__((ext_vector_type(4))) int int4v;
typedef __attribute__((ext_vector_type(4))) unsigned char uchar4v;

#if defined(__has_builtin)
#if __has_builtin(__builtin_amdgcn_cvt_pk_f32_fp8)
#define HAVE_CVT_FP8 1
#endif
#endif

__device__ __forceinline__ ushort_t f2bf(float f) {
    unsigned u = __float_as_uint(f);
    unsigned r = 0x7fffu + ((u >> 16) & 1u);   // round-to-nearest-even
    return (ushort_t)((u + r) >> 16);
}
__device__ __forceinline__ float bf2f(ushort_t h) {
    return __uint_as_float((unsigned)h << 16);
}

// ---- OCP fp8 e4m3fn encode (epilogue-side, RNE via 2^-120 scaling trick) ----
__device__ __forceinline__ uchar_t f2fp8(float f) {
    float a = fminf(fabsf(f), 448.f);
    unsigned u = __float_as_uint(a * 0x1p-120f);   // e4m3 em field lands at bits 20..26
    u += 0x7FFFFu + ((u >> 20) & 1u);              // RNE at bit 20
    unsigned em = (u >> 20) & 0x7Fu;
    unsigned sgn = (__float_as_uint(f) >> 24) & 0x80u;
    return (uchar_t)(sgn | em);
}

#ifdef HAVE_CVT_FP8
// HW decode: v_cvt_pk_f32_fp8 converts 2 OCP-e4m3 bytes -> 2 f32 per instruction.
#define FP8_POSTSCALE 1.0f
__device__ __forceinline__ void acc8_fp8(float* a, uint2 q) {
    float2v p0 = __builtin_amdgcn_cvt_pk_f32_fp8(q.x, false);  // bytes 0,1
    float2v p1 = __builtin_amdgcn_cvt_pk_f32_fp8(q.x, true);   // bytes 2,3
    float2v p2 = __builtin_amdgcn_cvt_pk_f32_fp8(q.y, false);
    float2v p3 = __builtin_amdgcn_cvt_pk_f32_fp8(q.y, true);
    a[0] += p0[0]; a[1] += p0[1]; a[2] += p1[0]; a[3] += p1[1];
    a[4] += p2[0]; a[5] += p2[1]; a[6] += p3[0]; a[7] += p3[1];
}
#else
// SW fallback: branch-free decode, raw value = true_value * 2^-120 (folded into inv scale)
#define FP8_POSTSCALE 0x1p120f
#define DEC0(w) __uint_as_float((((w) << 24) & 0x80000000u) | (((w) << 20) & 0x07f00000u))
#define DEC1(w) __uint_as_float((((w) << 16) & 0x80000000u) | (((w) << 12) & 0x07f00000u))
#define DEC2(w) __uint_as_float((((w) <<  8) & 0x80000000u) | (((w) <<  4) & 0x07f00000u))
#define DEC3(w) __uint_as_float((((w)      ) & 0x80000000u) | (((w) >>  4) & 0x07f00000u))
__device__ __forceinline__ void acc8_fp8(float* a, uint2 q) {
    a[0] += DEC0(q.x); a[1] += DEC1(q.x); a[2] += DEC2(q.x); a[3] += DEC3(q.x);
    a[4] += DEC0(q.y); a[5] += DEC1(q.y); a[6] += DEC2(q.y); a[7] += DEC3(q.y);
}
#endif

// ---------------- fused: cast x->bf16+fp8 + zero bcur  |  pack weights ----------------
__global__ __launch_bounds__(256) void cast_pack_k(const float* __restrict__ x,
                                                   ushort_t* __restrict__ xb,
                                                   uchar_t* __restrict__ xq,
                                                   int* __restrict__ bcur,
                                                   const float* __restrict__ W0n, const float* __restrict__ W0s,
                                                   const float* __restrict__ W1n, const float* __restrict__ W1s,
                                                   const float* __restrict__ W2n, const float* __restrict__ W2s,
                                                   ushort_t* __restrict__ P) {
    const int b = blockIdx.x, t = threadIdx.x;
    if (b < CAST_BLOCKS) {
        int i = b * 256 + t;
        if (i < N_NODES * 32) {
            float4 v = ((const float4*)x)[i];
            ushort4v h;
            h[0] = f2bf(v.x); h[1] = f2bf(v.y); h[2] = f2bf(v.z); h[3] = f2bf(v.w);
            ((ushort4v*)xb)[i] = h;
            uchar4v q;
            q[0] = f2fp8(v.x); q[1] = f2fp8(v.y); q[2] = f2fp8(v.z); q[3] = f2fp8(v.w);
            ((uchar4v*)xq)[i] = q;
        }
        if (i < 8) bcur[i] = 0;
        return;
    }
    // weight packing: fp32 W[128][DOUT] -> bf16 MFMA B-fragment layout
    int tid = (b - CAST_BLOCKS) * 256 + t;   // 0..10239
    const float* W; int dout; int base; int r;
    if      (tid < 2048)  { W = W0n; dout = 128; base = 0;     r = tid; }
    else if (tid < 4096)  { W = W0s; dout = 128; base = 16384; r = tid - 2048; }
    else if (tid < 6144)  { W = W1n; dout = 128; base = 32768; r = tid - 4096; }
    else if (tid < 8192)  { W = W1s; dout = 128; base = 49152; r = tid - 6144; }
    else if (tid < 9216)  { W = W2n; dout = 64;  base = 65536; r = tid - 8192; }
    else                  { W = W2s; dout = 64;  base = 73728; r = tid - 9216; }
    int lane = r & 63;
    int ks = (r >> 6) & 3;
    int nt = r >> 8;
    int col = nt * 16 + (lane & 15);
    int k0 = ks * 32 + ((lane >> 4) << 3);
    ushort_t* d = P + (size_t)base + (size_t)r * 8;
    ushort4v lo4, hi4;
#pragma unroll
    for (int j = 0; j < 4; ++j) lo4[j] = f2bf(W[(size_t)(k0 + j) * dout + col]);
#pragma unroll
    for (int j = 0; j < 4; ++j) hi4[j] = f2bf(W[(size_t)(k0 + 4 + j) * dout + col]);
    *(ushort4v*)d = lo4;
    *(ushort4v*)(d + 4) = hi4;
}

// ---------------- edge bucketing: 782 blocks x 4 edges/thread ----------------
__global__ __launch_bounds__(256) void bucket_k(const int4v* __restrict__ dst4,
                                                const int4v* __restrict__ src4,
                                                int* __restrict__ bcur,
                                                int2* __restrict__ buckets) {
    __shared__ int lcount[8];
    __shared__ int lbase[8];
    const int t = threadIdx.x, b = blockIdx.x;
    if (t < 8) lcount[t] = 0;
    __syncthreads();

    const int idx = b * 256 + t;   // int4 index, n4 = 200000
    int4v d, s;
    if (idx < N_EDGES / 4) {
        d = __builtin_nontemporal_load(dst4 + idx);
        s = __builtin_nontemporal_load(src4 + idx);
    } else {
        d[0] = d[1] = d[2] = d[3] = -1;
        s[0] = s[1] = s[2] = s[3] = 0;
    }
    int g[4], li[4];
#pragma unroll
    for (int j = 0; j < 4; ++j) {
        int dv = d[j];
        g[j] = (dv >= 0) ? (dv / NODES_PER_GRP) : -1;
        li[j] = (g[j] >= 0) ? atomicAdd(&lcount[g[j]], 1) : 0;
    }
    __syncthreads();
    if (t < 8) lbase[t] = atomicAdd(bcur + t, lcount[t]);
    __syncthreads();
#pragma unroll
    for (int j = 0; j < 4; ++j) {
        if (g[j] >= 0) {
            int pos = lbase[g[j]] + li[j];
            buckets[(size_t)g[j] * BUCKET_CAP + pos] = make_int2(d[j], s[j]);
        }
    }
}

// ---------------- atomic-free degree + chunk sums ----------------
__global__ __launch_bounds__(1024) void deg_hist_k(const int* __restrict__ bcur,
                                                   const int2* __restrict__ buckets,
                                                   int* __restrict__ deg,
                                                   int* __restrict__ bsum) {
    __shared__ int hist[NODES_PER_GRP];
    const int g = blockIdx.x;
    const int t = threadIdx.x;
    const int lo = g * NODES_PER_GRP;
    const int cnt = bcur[g];
    const int2* bk = buckets + (size_t)g * BUCKET_CAP;
    for (int i = t; i < NODES_PER_GRP; i += 1024) hist[i] = 0;
    __syncthreads();
    for (int i = t; i < cnt; i += 1024) {
        atomicAdd(&hist[bk[i].x - lo], 1);
    }
    __syncthreads();
    const int nNodes = (N_NODES - lo < NODES_PER_GRP) ? (N_NODES - lo) : NODES_PER_GRP;
    for (int i = t; i < nNodes; i += 1024) deg[lo + i] = hist[i];
    const int wave = t >> 6, lane = t & 63;
    const int nch = (nNodes + 255) >> 8;
    for (int c = wave; c < nch; c += 16) {
        int base = c * 256 + lane;
        int s = hist[base] + hist[base + 64] + hist[base + 128] + hist[base + 192];
#pragma unroll
        for (int off = 32; off > 0; off >>= 1) s += __shfl_xor(s, off);
        if (lane == 0) bsum[g * CHUNKS_PER_GRP + c] = s;
    }
}

// ---------------- fused rowptr ----------------
__global__ __launch_bounds__(256) void rowptr_fused_k(const int* __restrict__ deg,
                                                      const int* __restrict__ bsum,
                                                      int* __restrict__ rowptr,
                                                      int* __restrict__ cursor,
                                                      float* __restrict__ inv) {
    __shared__ int sb[256];
    __shared__ int s[256];
    const int t = threadIdx.x, b = blockIdx.x;
    int v = (t < NB_SCAN) ? bsum[t] : 0;
    sb[t] = v;
    __syncthreads();
#pragma unroll
    for (int off = 1; off < 256; off <<= 1) {
        int u = (t >= off) ? sb[t - off] : 0;
        __syncthreads();
        sb[t] += u;
        __syncthreads();
    }
    const int boffb = (b == 0) ? 0 : sb[b - 1];
    if (b == NB_SCAN - 1 && t == 0) rowptr[N_NODES] = sb[NB_SCAN - 1];

    int i = b * 256 + t;
    int d = (i < N_NODES) ? deg[i] : 0;
    s[t] = d;
    __syncthreads();
#pragma unroll
    for (int off = 1; off < 256; off <<= 1) {
        int u = (t >= off) ? s[t - off] : 0;
        __syncthreads();
        s[t] += u;
        __syncthreads();
    }
    if (i < N_NODES) {
        int r = boffb + s[t] - d;
        rowptr[i] = r;
        cursor[i] = r;
        inv[i] = 1.0f / fmaxf((float)d, 1.0f);
    }
}

// ---------------- scatter from buckets ----------------
__global__ __launch_bounds__(256) void scatter_bucket_k(const int* __restrict__ bcur,
                                                        const int2* __restrict__ buckets,
                                                        int* __restrict__ cursor,
                                                        int* __restrict__ csr) {
    const int grp = blockIdx.x & 7;
    const int cnt = bcur[grp];
    const int2* bk = buckets + (size_t)grp * BUCKET_CAP;
    const int stride = (gridDim.x >> 3) * 256;
    for (int i = (blockIdx.x >> 3) * 256 + threadIdx.x; i < cnt; i += stride) {
        int2 e = bk[i];
        csr[atomicAdd(cursor + e.x, 1)] = e.y;
    }
}

// ---------------- FUSED fp8-gather-mean + dual-A GEMM (32-row tile, high occupancy) ----------------
// 32-row tiles -> 1563 blocks, 16KB LDS -> ~6 blocks/CU resident: doubles the number of
// concurrently-gathering waves (round-19 analysis: gather is wave-count-limited, not MLP).
template <bool WQ>
__global__ __launch_bounds__(256, 6) void gathergemm_k(const ushort_t* __restrict__ H,
                                                       const uchar_t* __restrict__ Hq,
                                                       const int* __restrict__ rowptr,
                                                       const int* __restrict__ csr,
                                                       const float* __restrict__ inv,
                                                       const short8v* __restrict__ Ws,
                                                       const short8v* __restrict__ Wn,
                                                       const float* __restrict__ bias,
                                                       ushort_t* __restrict__ Out,
                                                       uchar_t* __restrict__ OutQ, int N) {
    __shared__ ushort_t sm[2][32 * 128];   // 2 x 8 KB
    char* sbH = (char*)sm[0];
    char* sbM = (char*)sm[1];
    const int bm = blockIdx.x * 32;
    const int t = threadIdx.x;
    const int w = t >> 6, l = t & 63;
    const ushort8v* Hp = (const ushort8v*)H;   // row stride 16 (256 B)
    const uint2* Qp = (const uint2*)Hq;        // row stride 16 (128 B)
    ushort8v zeroV = {0, 0, 0, 0, 0, 0, 0, 0};

    // stage H tile (swizzled): 2 passes of 16 rows
#pragma unroll
    for (int it = 0; it < 2; ++it) {
        int r = it * 16 + (t >> 4);
        int row = bm + r;
        int byte = (r * 256 + (t & 15) * 16) ^ ((r & 7) << 4);
        ushort8v vh = zeroV;
        if (row < N) vh = Hp[(size_t)row * 16 + (t & 15)];
        *(ushort8v*)(sbH + byte) = vh;
    }

    // fp8 gather-mean M tile straight into swizzled LDS: 16 lanes per row, 2 passes
    const int c = t & 15;
#pragma unroll
    for (int pass = 0; pass < 2; ++pass) {
        int r = pass * 16 + (t >> 4);
        int row = bm + r;
        int byte = (r * 256 + c * 16) ^ ((r & 7) << 4);
        ushort8v o = zeroV;
        if (row < N) {
            int start = rowptr[row], end = rowptr[row + 1];
            float a0[8] = {}, a1[8] = {}, a2[8] = {}, a3[8] = {};
            int j = start;
            for (; j + 7 < end; j += 8) {   // 8 loads in flight
                int u0 = csr[j],     u1 = csr[j + 1], u2 = csr[j + 2], u3 = csr[j + 3];
                int u4 = csr[j + 4], u5 = csr[j + 5], u6 = csr[j + 6], u7 = csr[j + 7];
                uint2 q0 = Qp[(size_t)u0 * 16 + c];
                uint2 q1 = Qp[(size_t)u1 * 16 + c];
                uint2 q2 = Qp[(size_t)u2 * 16 + c];
                uint2 q3 = Qp[(size_t)u3 * 16 + c];
                uint2 q4 = Qp[(size_t)u4 * 16 + c];
                uint2 q5 = Qp[(size_t)u5 * 16 + c];
                uint2 q6 = Qp[(size_t)u6 * 16 + c];
                uint2 q7 = Qp[(size_t)u7 * 16 + c];
                acc8_fp8(a0, q0); acc8_fp8(a1, q1);
                acc8_fp8(a2, q2); acc8_fp8(a3, q3);
                acc8_fp8(a0, q4); acc8_fp8(a1, q5);
                acc8_fp8(a2, q6); acc8_fp8(a3, q7);
            }
            for (; j + 3 < end; j += 4) {
                int u0 = csr[j], u1 = csr[j + 1], u2 = csr[j + 2], u3 = csr[j + 3];
                uint2 q0 = Qp[(size_t)u0 * 16 + c];
                uint2 q1 = Qp[(size_t)u1 * 16 + c];
                uint2 q2 = Qp[(size_t)u2 * 16 + c];
                uint2 q3 = Qp[(size_t)u3 * 16 + c];
                acc8_fp8(a0, q0); acc8_fp8(a1, q1);
                acc8_fp8(a2, q2); acc8_fp8(a3, q3);
            }
            for (; j < end; ++j) {
                uint2 q = Qp[(size_t)csr[j] * 16 + c];
                acc8_fp8(a0, q);
            }
            float scf = inv[row] * FP8_POSTSCALE;
#pragma unroll
            for (int k = 0; k < 8; ++k) o[k] = f2bf(((a0[k] + a1[k]) + (a2[k] + a3[k])) * scf);
        }
        *(ushort8v*)(sbM + byte) = o;
    }
    __syncthreads();

    // wave w: row-tile rt = w&1 (16 rows), col-tiles nt0..nt0+3 (64 cols)
    const int rt = w & 1;
    const int nt0 = (w >> 1) * 4;
    float bv[4];
#pragma unroll
    for (int nt = 0; nt < 4; ++nt) bv[nt] = bias[(nt0 + nt) * 16 + (l & 15)];

    float4v acc[4] = {};
#pragma unroll
    for (int ks = 0; ks < 4; ++ks) {
        int r0 = rt * 16 + (l & 15);
        int b0 = (r0 * 256 + ks * 64 + (l >> 4) * 16) ^ ((r0 & 7) << 4);
        short8v ah = *(const short8v*)(sbH + b0);
        short8v am = *(const short8v*)(sbM + b0);
#pragma unroll
        for (int nt = 0; nt < 4; ++nt) {
            short8v bs = Ws[((nt0 + nt) * 4 + ks) * 64 + l];
            short8v bn = Wn[((nt0 + nt) * 4 + ks) * 64 + l];
            acc[nt] = __builtin_amdgcn_mfma_f32_16x16x32_bf16(ah, bs, acc[nt], 0, 0, 0);
            acc[nt] = __builtin_amdgcn_mfma_f32_16x16x32_bf16(am, bn, acc[nt], 0, 0, 0);
        }
    }

    // C/D layout: col = lane&15, row = (lane>>4)*4 + i  [verified m89]
#pragma unroll
    for (int i = 0; i < 4; ++i) {
        int row = bm + rt * 16 + (l >> 4) * 4 + i;
        if (row < N) {
#pragma unroll
            for (int nt = 0; nt < 4; ++nt) {
                int col = (nt0 + nt) * 16 + (l & 15);
                float v = fmaxf(acc[nt][i] + bv[nt], 0.f);
                Out[(size_t)row * 128 + col] = f2bf(v);
                if (WQ) OutQ[(size_t)row * 128 + col] = f2fp8(v);
            }
        }
    }
}

// ---------------- layer-2 dual GEMM: S(fp32,->out) = H@Wself + b ; Z(bf16) = H@Wneigh ----------------
__global__ __launch_bounds__(256, 4) void dual64_k(const ushort_t* __restrict__ A,
                                                   const short8v* __restrict__ Wn,
                                                   const short8v* __restrict__ Ws,
                                                   const float* __restrict__ bias,
                                                   ushort_t* __restrict__ Z,
                                                   float* __restrict__ S, int N) {
    constexpr int NT = 4;
    __shared__ ushort_t Asm[64 * 128];   // 16 KB
    char* sb = (char*)Asm;
    const int bm = blockIdx.x * 64;
    const int t = threadIdx.x;
    const int w = t >> 6, l = t & 63;

    {
        const ushort8v* Ap = (const ushort8v*)A;
        ushort8v zeroV = {0, 0, 0, 0, 0, 0, 0, 0};
#pragma unroll
        for (int it = 0; it < 4; ++it) {
            int r = it * 16 + (t >> 4);
            int row = bm + r;
            ushort8v v = zeroV;
            if (row < N) v = Ap[(size_t)row * 16 + (t & 15)];
            int byte = (r * 256 + (t & 15) * 16) ^ ((r & 7) << 4);
            *(ushort8v*)(sb + byte) = v;
        }
    }
    __syncthreads();

    float bv[NT];
#pragma unroll
    for (int nt = 0; nt < NT; ++nt) bv[nt] = bias[nt * 16 + (l & 15)];

    float4v accS[NT] = {}, accN[NT] = {};
#pragma unroll
    for (int ks = 0; ks < 4; ++ks) {
        int r0 = w * 16 + (l & 15);
        int b0 = (r0 * 256 + ks * 64 + (l >> 4) * 16) ^ ((r0 & 7) << 4);
        short8v a = *(const short8v*)(sb + b0);
#pragma unroll
        for (int nt = 0; nt < NT; ++nt) {
            short8v bs = Ws[(nt * 4 + ks) * 64 + l];
            short8v bn = Wn[(nt * 4 + ks) * 64 + l];
            accS[nt] = __builtin_amdgcn_mfma_f32_16x16x32_bf16(a, bs, accS[nt], 0, 0, 0);
            accN[nt] = __builtin_amdgcn_mfma_f32_16x16x32_bf16(a, bn, accN[nt], 0, 0, 0);
        }
    }

#pragma unroll
    for (int i = 0; i < 4; ++i) {
        int row = bm + w * 16 + (l >> 4) * 4 + i;
        if (row < N) {
#pragma unroll
            for (int nt = 0; nt < NT; ++nt) {
                int col = nt * 16 + (l & 15);
                S[(size_t)row * 64 + col] = accS[nt][i] + bv[nt];
                Z[(size_t)row * 64 + col] = f2bf(accN[nt][i]);
            }
        }
    }
}

// ---------------- layer-2 aggregation: out(fp32,=S) += inv * sum z[nbr]  (64-wide, bf16) ----------------
__global__ __launch_bounds__(256) void agg64_k(const ushort_t* __restrict__ z,
                                               const int* __restrict__ rowptr,
                                               const int* __restrict__ csr,
                                               const float* __restrict__ inv,
                                               float* __restrict__ out, int N) {
    int node = (blockIdx.x * 256 + threadIdx.x) >> 3;
    int c = threadIdx.x & 7;
    if (node >= N) return;
    int start = rowptr[node], end = rowptr[node + 1];

    const ushort8v* zp = (const ushort8v*)z;   // row stride 8 (128 B)
    float a0[8] = {}, a1[8] = {}, a2[8] = {}, a3[8] = {};
    int j = start;
    for (; j + 3 < end; j += 4) {
        int u0 = csr[j], u1 = csr[j + 1], u2 = csr[j + 2], u3 = csr[j + 3];
        ushort8v w0 = zp[(size_t)u0 * 8 + c];
        ushort8v w1 = zp[(size_t)u1 * 8 + c];
        ushort8v w2 = zp[(size_t)u2 * 8 + c];
        ushort8v w3 = zp[(size_t)u3 * 8 + c];
#pragma unroll
        for (int k = 0; k < 8; ++k) {
            a0[k] += bf2f(w0[k]); a1[k] += bf2f(w1[k]);
            a2[k] += bf2f(w2[k]); a3[k] += bf2f(w3[k]);
        }
    }
    for (; j < end; ++j) {
        ushort8v w = zp[(size_t)csr[j] * 8 + c];
#pragma unroll
        for (int k = 0; k < 8; ++k) a0[k] += bf2f(w[k]);
    }
    float s = inv[node];
    float* op = out + (size_t)node * 64 + c * 8;
    float4 o0 = *(float4*)op;
    float4 o1 = *(float4*)(op + 4);
    o0.x += ((a0[0] + a1[0]) + (a2[0] + a3[0])) * s;
    o0.y += ((a0[1] + a1[1]) + (a2[1] + a3[1])) * s;
    o0.z += ((a0[2] + a1[2]) + (a2[2] + a3[2])) * s;
    o0.w += ((a0[3] + a1[3]) + (a2[3] + a3[3])) * s;
    o1.x += ((a0[4] + a1[4]) + (a2[4] + a3[4])) * s;
    o1.y += ((a0[5] + a1[5]) + (a2[5] + a3[5])) * s;
    o1.z += ((a0[6] + a1[6]) + (a2[6] + a3[6])) * s;
    o1.w += ((a0[7] + a1[7]) + (a2[7] + a3[7])) * s;
    *(float4*)op = o0;
    *(float4*)(op + 4) = o1;
}

// ---------------- launch ----------------

extern "C" void kernel_launch(void* const* d_in, const int* in_sizes, int n_in,
                              void* d_out, int out_size, void* d_ws, size_t ws_size,
                              hipStream_t stream) {
    const float* x       = (const float*)d_in[0];
    const int*   src     = (const int*)d_in[1];
    const int*   dst     = (const int*)d_in[2];
    const float* Wself0  = (const float*)d_in[3];
    const float* Wneigh0 = (const float*)d_in[4];
    const float* b0      = (const float*)d_in[5];
    const float* Wself1  = (const float*)d_in[6];
    const float* Wneigh1 = (const float*)d_in[7];
    const float* b1      = (const float*)d_in[8];
    const float* Wself2  = (const float*)d_in[9];
    const float* Wneigh2 = (const float*)d_in[10];
    const float* b2      = (const float*)d_in[11];
    float* out = (float*)d_out;

    char* ws = (char*)d_ws;
    size_t off = 0;
    auto alloc = [&](size_t bytes) -> void* {
        void* p = ws + off;
        off += (bytes + 255) & ~(size_t)255;
        return p;
    };
    int*      deg     = (int*)alloc((size_t)N_NODES * 4);
    float*    inv     = (float*)alloc((size_t)N_NODES * 4);
    int*      rowptr  = (int*)alloc((size_t)(N_NODES + 1) * 4);
    int*      cursor  = (int*)alloc((size_t)N_NODES * 4);
    int*      csr     = (int*)alloc((size_t)N_EDGES * 4);
    int*      bsum    = (int*)alloc((size_t)NB_SCAN * 4);
    int*      bcur    = (int*)alloc((size_t)8 * 4);
    int2*     buckets = (int2*)alloc((size_t)8 * BUCKET_CAP * 8);
    ushort_t* packW   = (ushort_t*)alloc((size_t)81920 * 2);
    ushort_t* xb      = (ushort_t*)alloc((size_t)N_NODES * 128 * 2);
    uchar_t*  xq      = (uchar_t*)alloc((size_t)N_NODES * 128);
    ushort_t* h1      = (ushort_t*)alloc((size_t)N_NODES * 128 * 2);
    uchar_t*  h1q     = (uchar_t*)alloc((size_t)N_NODES * 128);
    ushort_t* h2      = (ushort_t*)alloc((size_t)N_NODES * 128 * 2);
    ushort_t* z64     = (ushort_t*)alloc((size_t)N_NODES * 64 * 2);

    dim3 b256(256);
    const int ggBlocks     = (N_NODES + 31) / 32;          // 1563 (32-row tiles)
    const int gemmBlocks   = (N_NODES + 63) / 64;          // 782 (dual64, 64-row tiles)
    const int agg64Blocks  = (N_NODES * 8 + 255) / 256;    // 1563
    const int bucketBlocks = (N_EDGES / 4 + 255) / 256;    // 782 (4 edges/thread)

    // ---- CSR build: cast+pack | bucket | LDS-hist deg+chunk-sums | rowptr | scatter ----
    cast_pack_k<<<CAST_BLOCKS + 40, b256, 0, stream>>>(x, xb, xq, bcur,
                                                       Wneigh0, Wself0, Wneigh1, Wself1,
                                                       Wneigh2, Wself2, packW);
    bucket_k<<<bucketBlocks, b256, 0, stream>>>((const int4v*)dst, (const int4v*)src,
                                                bcur, buckets);
    deg_hist_k<<<8, dim3(1024), 0, stream>>>(bcur, buckets, deg, bsum);
    rowptr_fused_k<<<NB_SCAN, b256, 0, stream>>>(deg, bsum, rowptr, cursor, inv);
    scatter_bucket_k<<<512, b256, 0, stream>>>(bcur, buckets, cursor, csr);

    const short8v* pN0 = (const short8v*)(packW);
    const short8v* pS0 = (const short8v*)(packW + 16384);
    const short8v* pN1 = (const short8v*)(packW + 32768);
    const short8v* pS1 = (const short8v*)(packW + 49152);
    const short8v* pN2 = (const short8v*)(packW + 65536);
    const short8v* pS2 = (const short8v*)(packW + 73728);

    // layer 0: h1 = relu(xb@Ws0 + mean_fp8(xq[nbr])@Wn0 + b0); also writes h1q (fp8 shadow)
    gathergemm_k<true><<<ggBlocks, b256, 0, stream>>>(xb, xq, rowptr, csr, inv,
                                                      pS0, pN0, b0, h1, h1q, N_NODES);

    // layer 1: h2 = relu(h1@Ws1 + mean_fp8(h1q[nbr])@Wn1 + b1)
    gathergemm_k<false><<<ggBlocks, b256, 0, stream>>>(h1, h1q, rowptr, csr, inv,
                                                       pS1, pN1, b1, h2, nullptr, N_NODES);

    // layer 2 (gemm-first, bf16 z): out = h2@Ws2 + b2 ; z = bf16(h2@Wn2) ; out += inv*segsum(z)
    dual64_k<<<gemmBlocks, b256, 0, stream>>>(h2, pN2, pS2, b2, z64, out, N_NODES);
    agg64_k<<<agg64Blocks, b256, 0, stream>>>(z64, rowptr, csr, inv, out, N_NODES);
}